// Round 15
// baseline (205.592 us; speedup 1.0000x reference)
//
#include <hip/hip_runtime.h>

#define V 128000
#define V4 (V / 4)
#define NROWS 256
#define V4ALL (NROWS * V4)
#define NCHUNK (V / 16)      // 8000 chunk-max entries
#define NSLICE 8
#define SL4 (V4 / NSLICE)    // 4000 float4 per slice
#define SLC (NCHUNK / NSLICE)// 1000 chunks per slice
#define W 200
#define VW (V / 32)
#define CAP 4096             // candidate capacity
#define CAPS 2048            // survivor capacity
#define CAPM 8192            // mono-kernel capacity
#define TINYF 1.17549435e-38f
#define HIDX(b) ((b) + ((b) >> 5))
#define HSZ 4224

// ---- d_ws layout ----
#define WS_CMAX   0u          // u16[256][8000] = 4,096,000
#define WS_BMAX   4104192u    // float[256][8]
#define WS_B0     4112384u    // int[256]
#define WS_CNT    4113408u    // int[256]
#define WS_KEYS   8388608u    // u64[256][4096] = 8 MiB
#define WS_NEED   16777216u

typedef float vfloat4 __attribute__((ext_vector_type(4)));

__device__ __forceinline__ void bar_lds() {
  asm volatile("s_waitcnt lgkmcnt(0)" ::: "memory");
  __builtin_amdgcn_s_barrier();
}

__device__ __forceinline__ unsigned int fkey(float x) {
  unsigned int u = __float_as_uint(x);
  return (u & 0x80000000u) ? ~u : (u | 0x80000000u);
}
__device__ __forceinline__ float ikey(unsigned int k) {
  unsigned int u = (k & 0x80000000u) ? (k & 0x7FFFFFFFu) : ~k;
  return __uint_as_float(u);
}

// ---- jax threefry2x32, partitionable: counter=(0,t), key=(0,42), fold=xor ----
__device__ __forceinline__ unsigned int tf_bits(unsigned int t) {
  const unsigned int k0 = 0u, k1 = 42u;
  const unsigned int ks2 = k0 ^ k1 ^ 0x1BD11BDAu;
  unsigned int x0 = 0u + k0, x1 = t + k1;
  const unsigned int ksArr[3] = {k0, k1, ks2};
  const int RA[4] = {13, 15, 26, 6};
  const int RB[4] = {17, 29, 16, 24};
#pragma unroll
  for (int i = 0; i < 5; ++i) {
#pragma unroll
    for (int j = 0; j < 4; ++j) {
      int r = (i & 1) ? RB[j] : RA[j];
      x0 += x1;
      x1 = (x1 << r) | (x1 >> (32 - r));
      x1 ^= x0;
    }
    x0 += ksArr[(i + 1) % 3];
    x1 += ksArr[(i + 2) % 3] + (unsigned int)(i + 1);
  }
  return x0 ^ x1;
}

__device__ __forceinline__ float xform(float x, bool seen, float rp, float irp,
                                        float itemp) {
  if (seen) x = (x > 0.0f) ? x * irp : x * rp;
  return x * itemp;
}

// Wave-parallel suffix select over a padded 4096-bucket histogram (one wave).
__device__ __forceinline__ void wave_suffix_select_p(const int* hist, int need,
                                                     int lane, int* out_b,
                                                     int* out_rem) {
  int sm = 0;
  const int bb = lane * 64;
  for (int i = 0; i < 64; ++i) sm += hist[HIDX(bb + i)];
  int sfx = sm;
#pragma unroll
  for (int d = 1; d < 64; d <<= 1) {
    int t = __shfl_down(sfx, d);
    if (lane + d < 64) sfx += t;
  }
  unsigned long long mk = __ballot(sfx >= need);
  const int cstar = 63 - __builtin_clzll(mk);
  const int aboveC = __shfl(sfx, cstar) - __shfl(sm, cstar);
  int h = hist[HIDX(cstar * 64 + lane)];
  int sfx2 = h;
#pragma unroll
  for (int d = 1; d < 64; d <<= 1) {
    int t = __shfl_down(sfx2, d);
    if (lane + d < 64) sfx2 += t;
  }
  unsigned long long mk2 = __ballot(aboveC + sfx2 >= need);
  const int boff = 63 - __builtin_clzll(mk2);
  const int aboveB = aboveC + __shfl(sfx2, boff) - __shfl(h, boff);
  if (lane == 0) {
    *out_b = cstar * 64 + boff;
    *out_rem = need - aboveB;
  }
}

// ====== Kernel F: zero-fill probs at full write bandwidth ======
__global__ __launch_bounds__(256) void kF_zero(float* __restrict__ probs) {
  vfloat4* __restrict__ p4 = reinterpret_cast<vfloat4*>(probs);
  const vfloat4 z4 = (vfloat4){0.0f, 0.0f, 0.0f, 0.0f};
  const int stride = gridDim.x * 256;
  for (int q = blockIdx.x * 256 + threadIdx.x; q < V4ALL; q += stride)
    p4[q] = z4;
}

// ====== Kernel A: transform + chunk-max + slice-max (pure read) ======
__global__ __launch_bounds__(256) void kA_chunkmax(
    const float* __restrict__ logits, const int* __restrict__ toks,
    const float* __restrict__ temps, const float* __restrict__ rps,
    unsigned short* __restrict__ ws_cmax, float* __restrict__ ws_bmax) {
  __shared__ unsigned int s_seen[VW];
  __shared__ float s_red[4];
  const int row = blockIdx.x >> 3;
  const int slice = blockIdx.x & 7;
  const int tid = threadIdx.x;
  const int lane = tid & 63;
  const int wid = tid >> 6;
  const float rp = rps[row];
  const float irp = 1.0f / rp;
  const float itemp = 1.0f / temps[row];
  const size_t base = (size_t)row * V;
  const float4* __restrict__ lg4 = reinterpret_cast<const float4*>(logits + base);

  for (int i = tid; i < VW; i += 256) s_seen[i] = 0u;
  __syncthreads();
  for (int i = tid; i < W; i += 256) {
    int tok = toks[row * W + i];
    if (tok >= 0 && tok < V) atomicOr(&s_seen[tok >> 5], 1u << (tok & 31));
  }
  __syncthreads();

  float lmax = -INFINITY;
  const int q0 = slice * SL4;
  for (int qi = tid; qi < SL4; qi += 256) {
    const int q = q0 + qi;
    float4 x4 = lg4[q];
    float xs[4] = {x4.x, x4.y, x4.z, x4.w};
    const int j0 = q * 4;
    const int sh = j0 & 31;
    unsigned long long ww = (unsigned long long)s_seen[j0 >> 5] |
                            ((unsigned long long)s_seen[(j0 + 3) >> 5] << 32);
    unsigned int kmax = 0u;
#pragma unroll
    for (int e = 0; e < 4; ++e) {
      float x = xform(xs[e], (ww >> (sh + e)) & 1ull, rp, irp, itemp);
      lmax = fmaxf(lmax, x);
      unsigned int ky = fkey(x);
      kmax = kmax > ky ? kmax : ky;
    }
    unsigned int o;
    o = __shfl_xor(kmax, 1); kmax = kmax > o ? kmax : o;
    o = __shfl_xor(kmax, 2); kmax = kmax > o ? kmax : o;
    if ((lane & 3) == 0) ws_cmax[row * NCHUNK + (q >> 2)] = (unsigned short)(kmax >> 16);
  }
#pragma unroll
  for (int d = 32; d > 0; d >>= 1) lmax = fmaxf(lmax, __shfl_xor(lmax, d));
  if (lane == 0) s_red[wid] = lmax;
  __syncthreads();
  if (tid == 0) {
    float mm = fmaxf(fmaxf(s_red[0], s_red[1]), fmaxf(s_red[2], s_red[3]));
    ws_bmax[row * NSLICE + slice] = mm;
  }
}

// ====== Kernel S: per-row b0 select from chunk-max histogram (4x replicated) ======
__global__ __launch_bounds__(1024) void kS_b0(
    const unsigned short* __restrict__ ws_cmax, const int* __restrict__ topks,
    int* __restrict__ ws_b0, int* __restrict__ ws_cnt) {
  __shared__ int s_h[4 * HSZ];   // 67.6 KB
  __shared__ int s_b, s_rem;
  const int row = blockIdx.x;
  const int tid = threadIdx.x;
  const int lane = tid & 63;
  const int wid = tid >> 6;
  for (int i = tid; i < 4 * HSZ; i += 1024) s_h[i] = 0;
  __syncthreads();
  const unsigned short* cm = ws_cmax + row * NCHUNK;
  const int rep = (tid & 3) * HSZ;
  for (int i = tid; i < NCHUNK; i += 1024)
    atomicAdd(&s_h[rep + HIDX(cm[i] >> 4)], 1);
  __syncthreads();
  for (int i = tid; i < HSZ; i += 1024)
    s_h[i] += s_h[i + HSZ] + s_h[i + 2 * HSZ] + s_h[i + 3 * HSZ];
  __syncthreads();
  if (wid == 0) wave_suffix_select_p(s_h, topks[row], lane, &s_b, &s_rem);
  __syncthreads();
  if (tid == 0) {
    ws_b0[row] = s_b;
    ws_cnt[row] = 0;
  }
}

// ====== Kernel B1: gather candidates to ws (8 slices/row, 8 blocks/CU) ======
// NOTE: uniform-trip loop — every thread executes every iteration so the
// wave-wide shuffles/ballots below are wave-uniform (SL4 % 256 != 0!).
__global__ __launch_bounds__(256) void kB1_gather(
    const float* __restrict__ logits, const int* __restrict__ toks,
    const float* __restrict__ temps, const float* __restrict__ rps,
    const unsigned short* __restrict__ ws_cmax, const int* __restrict__ ws_b0,
    int* __restrict__ ws_cnt, unsigned long long* __restrict__ ws_keys) {
  __shared__ unsigned int s_seen[VW];     // 16 KB
  __shared__ unsigned short s_cm[SLC];    // 2 KB
  const int row = blockIdx.x >> 3;
  const int slice = blockIdx.x & 7;
  const int tid = threadIdx.x;
  const int lane = tid & 63;
  const float rp = rps[row];
  const float irp = 1.0f / rp;
  const float itemp = 1.0f / temps[row];
  const size_t base = (size_t)row * V;
  const float4* __restrict__ lg4 = reinterpret_cast<const float4*>(logits + base);

  for (int i = tid; i < VW; i += 256) s_seen[i] = 0u;
  for (int i = tid; i < SLC; i += 256)
    s_cm[i] = ws_cmax[row * NCHUNK + slice * SLC + i];
  __syncthreads();
  for (int i = tid; i < W; i += 256) {
    int tok = toks[row * W + i];
    if (tok >= 0 && tok < V) atomicOr(&s_seen[tok >> 5], 1u << (tok & 31));
  }
  __syncthreads();

  const int b0 = ws_b0[row];
  const unsigned int fk0 = ((unsigned int)b0) << 20;
  const int c16 = b0 << 4;
  unsigned long long* __restrict__ krow = ws_keys + (size_t)row * CAP;
  const int q0 = slice * SL4;
  for (int qb = 0; qb < SL4; qb += 256) {
    const int qi = qb + tid;
    const bool inb = (qi < SL4);
    const bool act = inb && ((int)s_cm[qi >> 2] >= c16);
    const int q = q0 + qi;
    const int j0 = q * 4;
    unsigned int ks[4];
    bool pr[4] = {false, false, false, false};
    if (act) {
      float4 x4 = lg4[q];
      float raw[4] = {x4.x, x4.y, x4.z, x4.w};
      const int sh = j0 & 31;
      unsigned long long ww = (unsigned long long)s_seen[j0 >> 5] |
                              ((unsigned long long)s_seen[(j0 + 3) >> 5] << 32);
#pragma unroll
      for (int e = 0; e < 4; ++e) {
        float x = xform(raw[e], (ww >> (sh + e)) & 1ull, rp, irp, itemp);
        ks[e] = fkey(x);
        pr[e] = (ks[e] >= fk0);
      }
    }
    int cnt = (int)pr[0] + (int)pr[1] + (int)pr[2] + (int)pr[3];
    int inc = cnt;
#pragma unroll
    for (int d = 1; d < 64; d <<= 1) {
      int t = __shfl_up(inc, d);
      if (lane >= d) inc += t;
    }
    const int total = __shfl(inc, 63);
    if (total) {
      int basep = 0;
      if (lane == 0) basep = atomicAdd(&ws_cnt[row], total);
      basep = __shfl(basep, 0);
      int off = basep + inc - cnt;
#pragma unroll
      for (int e = 0; e < 4; ++e) {
        if (pr[e]) {
          if (off < CAP)
            krow[off] = ((unsigned long long)ks[e] << 32) | (unsigned int)(j0 + e);
          ++off;
        }
      }
    }
  }
}

// ====== Kernel B2: radix-kth + compact + counting sort + top-p + sample + scatter ======
__global__ __launch_bounds__(1024) void kB2_finish(
    const float* __restrict__ topps, const int* __restrict__ topks,
    const float* __restrict__ ws_bmax, const int* __restrict__ ws_cnt,
    const unsigned long long* __restrict__ ws_keys,
    float* __restrict__ out_ids, float* __restrict__ probs) {
  __shared__ unsigned long long s_key[CAP];             // 32 KB: keys; later sorted+overlays
  __shared__ __align__(16) int s_h[4 * HSZ];            // 67.6 KB: replicated hists -> keep
  __shared__ __align__(16) unsigned char s_bufB[16384]; // 16 KB: survivors (unsorted)
  __shared__ float s_wredf[16];
  __shared__ int s_wredi[16];
  __shared__ float s_mv, s_dn1, s_dn2;
  __shared__ int s_scnt, s_selb, s_selrem, s_p0v, s_maxpop;

  unsigned long long* s_key2 = (unsigned long long*)s_bufB;
  unsigned long long* s_skey = s_key;
  float* s_e2 = (float*)(s_key + CAPS);
  float* s_q2 = (float*)(s_key + CAPS + CAPS / 2);
  unsigned char* s_keep = (unsigned char*)s_h;          // overlay (hists dead post-sort)

  const int row = blockIdx.x;
  const int tid = threadIdx.x;
  const int lane = tid & 63;
  const int wid = tid >> 6;
  const float topp = topps[row];
  const int k = topks[row];
  float* __restrict__ prow = probs + (size_t)row * V;

  int G = ws_cnt[row];
  if (G > CAP) G = CAP;
  const int kk = k > G ? G : k;
  {
    const unsigned long long* krow = ws_keys + (size_t)row * CAP;
    for (int i = tid; i < G; i += 1024) s_key[i] = krow[i];
  }
  if (wid == 1 && lane == 0) {
    float mm = ws_bmax[row * NSLICE];
    for (int i = 1; i < NSLICE; ++i) mm = fmaxf(mm, ws_bmax[row * NSLICE + i]);
    s_mv = mm;
  }
  for (int i = tid; i < 4 * HSZ; i += 1024) s_h[i] = 0;
  __syncthreads();

  // ---- 1-pass radix (replicated): bucket (fkey>>20) of the kk-th largest ----
  const int rep = (tid & 3) * HSZ;
  for (int i = tid; i < G; i += 1024)
    atomicAdd(&s_h[rep + HIDX((unsigned int)(s_key[i] >> 52))], 1);
  bar_lds();
  for (int i = tid; i < HSZ; i += 1024)
    s_h[i] += s_h[i + HSZ] + s_h[i + 2 * HSZ] + s_h[i + 3 * HSZ];
  bar_lds();
  if (wid == 0) {
    wave_suffix_select_p(s_h, kk, lane, &s_selb, &s_selrem);
    if (lane == 0) s_scnt = 0;
  }
  bar_lds();
  const unsigned int b1 = (unsigned int)s_selb;

  // ---- compact survivor-superset (top12 >= b1) into s_key2 ----
  for (int ib = 0; ib < G; ib += 1024) {
    const int i = ib + tid;
    const bool p = (i < G) && ((unsigned int)(s_key[i] >> 52) >= b1);
    unsigned long long mask = __ballot(p);
    if (!mask) continue;
    int basep = 0;
    if (lane == 0) basep = atomicAdd(&s_scnt, __popcll(mask));
    basep = __shfl(basep, 0);
    if (p) {
      int pos = basep + __popcll(mask & ((1ull << lane) - 1ull));
      if (pos < CAPS) s_key2[pos] = s_key[i];
    }
  }
  bar_lds();
  int S = s_scnt;
  if (S > CAPS) S = CAPS;
  const float m = s_mv;

  // ---- counting sort by value bins (replicated counts), bitonic fallback ----
  const unsigned int cbase = b1 << 20;
  const unsigned int span = fkey(m) - cbase;
  int shiftb;
  {
    int bits = 32 - __clz((int)(span | 1u));
    shiftb = bits > 12 ? bits - 12 : 0;
  }
  for (int i = tid; i < 4 * HSZ; i += 1024) s_h[i] = 0;
  bar_lds();
  for (int i = tid; i < S; i += 1024) {
    unsigned int hi = (unsigned int)(s_key2[i] >> 32);
    int b = (int)((hi - cbase) >> shiftb);
    if (b > 4095) b = 4095;
    atomicAdd(&s_h[rep + HIDX(b)], 1);
  }
  bar_lds();
  for (int i = tid; i < HSZ; i += 1024)
    s_h[i] += s_h[i + HSZ] + s_h[i + 2 * HSZ] + s_h[i + 3 * HSZ];
  bar_lds();
  if (wid == 0) {
    int T = 0, mx = 0;
    const int bb = lane * 64;
    for (int i = 0; i < 64; ++i) {
      int c = s_h[HIDX(bb + i)];
      T += c;
      mx = c > mx ? c : mx;
    }
    int ex = T;
#pragma unroll
    for (int d = 1; d < 64; d <<= 1) {
      int t = __shfl_up(ex, d);
      if (lane >= d) ex += t;
    }
    ex -= T;
    int run = ex;
    for (int i = 0; i < 64; ++i) {
      int idx = HIDX(bb + i);
      int c = s_h[idx];
      s_h[idx] = run;
      run += c;
    }
#pragma unroll
    for (int d = 32; d > 0; d >>= 1) {
      int o = __shfl_xor(mx, d);
      mx = o > mx ? o : mx;
    }
    if (lane == 0) s_maxpop = mx;
  }
  bar_lds();

  if (s_maxpop <= 16) {
    for (int i = tid; i < S; i += 1024) {
      unsigned long long key = s_key2[i];
      unsigned int hi = (unsigned int)(key >> 32);
      int b = (int)((hi - cbase) >> shiftb);
      if (b > 4095) b = 4095;
      int pos = atomicAdd(&s_h[HIDX(b)], 1);
      s_skey[pos] = key;
    }
    bar_lds();
    for (int b = tid; b < 4096; b += 1024) {
      int endb = s_h[HIDX(b)];
      int st = (b == 0) ? 0 : s_h[HIDX(b - 1)];
      for (int i = st + 1; i < endb; ++i) {
        unsigned long long key = s_skey[i];
        int j = i - 1;
        while (j >= st && s_skey[j] > key) {
          s_skey[j + 1] = s_skey[j];
          --j;
        }
        s_skey[j + 1] = key;
      }
    }
    bar_lds();
  } else {
    int np2 = 2;
    while (np2 < S) np2 <<= 1;
    for (int i = S + tid; i < np2; i += 1024) s_key2[i] = ~0ull;
    bar_lds();
    for (int size = 2; size <= np2; size <<= 1) {
      for (int stride = size >> 1; stride > 0; stride >>= 1) {
        for (int t2 = tid; t2 < (np2 >> 1); t2 += 1024) {
          int pos = 2 * t2 - (t2 & (stride - 1));
          int qq = pos + stride;
          bool up = ((pos & size) == 0);
          unsigned long long a = s_key2[pos], b = s_key2[qq];
          if ((a > b) == up) { s_key2[pos] = b; s_key2[qq] = a; }
        }
        bar_lds();
      }
    }
    for (int i = tid; i < S; i += 1024) s_skey[i] = s_key2[i];
    bar_lds();
  }

  // ---- exact kth + survivor range [p0, S) ----
  const unsigned int kthkey32 = (unsigned int)(s_skey[S - kk] >> 32);
  for (int i = tid; i < S; i += 1024) {
    unsigned int hi = (unsigned int)(s_skey[i] >> 32);
    if (hi >= kthkey32 && (i == 0 || (unsigned int)(s_skey[i - 1] >> 32) < kthkey32))
      s_p0v = i;
  }
  bar_lds();
  const int p0 = s_p0v;
  const int L = S - p0;

  // ---- softmax denom over survivors ----
  float part = 0.0f;
  for (int i = tid; i < L; i += 1024) {
    float x = ikey((unsigned int)(s_skey[p0 + i] >> 32));
    float e = expf(x - m);
    s_e2[i] = e;
    part += e;
  }
#pragma unroll
  for (int d = 32; d > 0; d >>= 1) part += __shfl_xor(part, d);
  if (lane == 0) s_wredf[wid] = part;
  bar_lds();
  if (tid == 0) {
    float s = 0.0f;
    for (int i = 0; i < 16; ++i) s += s_wredf[i];
    s_dn1 = s;
  }
  bar_lds();
  const float denom = s_dn1;

  for (int i = tid; i < L; i += 1024) s_q2[i] = s_e2[i] / denom;
  bar_lds();

  // ---- serial fp32 cumsum (pure add chain) + top-p mask, last kept ----
  if (tid == 0) {
    const float cut = 1.0f - topp;
    float cs = 0.0f;
    int i = 0;
    for (; i + 16 <= L; i += 16) {
      vfloat4 a = *(const vfloat4*)&s_q2[i];
      vfloat4 b = *(const vfloat4*)&s_q2[i + 4];
      vfloat4 c = *(const vfloat4*)&s_q2[i + 8];
      vfloat4 d = *(const vfloat4*)&s_q2[i + 12];
      unsigned int w0, w1, w2, w3;
      cs += a.x; w0  = (cs <= cut) ? 0u : 1u;
      cs += a.y; w0 |= ((cs <= cut) ? 0u : 1u) << 8;
      cs += a.z; w0 |= ((cs <= cut) ? 0u : 1u) << 16;
      cs += a.w; w0 |= ((cs <= cut) ? 0u : 1u) << 24;
      cs += b.x; w1  = (cs <= cut) ? 0u : 1u;
      cs += b.y; w1 |= ((cs <= cut) ? 0u : 1u) << 8;
      cs += b.z; w1 |= ((cs <= cut) ? 0u : 1u) << 16;
      cs += b.w; w1 |= ((cs <= cut) ? 0u : 1u) << 24;
      cs += c.x; w2  = (cs <= cut) ? 0u : 1u;
      cs += c.y; w2 |= ((cs <= cut) ? 0u : 1u) << 8;
      cs += c.z; w2 |= ((cs <= cut) ? 0u : 1u) << 16;
      cs += c.w; w2 |= ((cs <= cut) ? 0u : 1u) << 24;
      cs += d.x; w3  = (cs <= cut) ? 0u : 1u;
      cs += d.y; w3 |= ((cs <= cut) ? 0u : 1u) << 8;
      cs += d.z; w3 |= ((cs <= cut) ? 0u : 1u) << 16;
      cs += d.w; w3 |= ((cs <= cut) ? 0u : 1u) << 24;
      *(unsigned int*)&s_keep[i] = w0;
      *(unsigned int*)&s_keep[i + 4] = w1;
      *(unsigned int*)&s_keep[i + 8] = w2;
      *(unsigned int*)&s_keep[i + 12] = w3;
    }
    for (; i < L; ++i) {
      cs += s_q2[i];
      s_keep[i] = (cs <= cut) ? 0 : 1;
    }
    s_keep[L - 1] = 1;
  }
  bar_lds();

  // ---- final denom over kept ----
  part = 0.0f;
  for (int i = tid; i < L; i += 1024)
    if (s_keep[i]) part += s_e2[i];
#pragma unroll
  for (int d = 32; d > 0; d >>= 1) part += __shfl_xor(part, d);
  if (lane == 0) s_wredf[wid] = part;
  bar_lds();
  if (tid == 0) {
    float s = 0.0f;
    for (int i = 0; i < 16; ++i) s += s_wredf[i];
    s_dn2 = s;
  }
  bar_lds();
  const float denom2 = s_dn2;

  for (int i = tid; i < L; i += 1024)
    s_e2[i] = s_keep[i] ? (s_e2[i] / denom2) : 0.0f;
  bar_lds();

  // ---- Gumbel argmax over kept survivors ----
  float bs = -INFINITY;
  int bi = 0x7FFFFFFF;
  for (int i = tid; i < L; i += 1024) {
    if (!s_keep[i]) continue;
    unsigned long long kv = s_skey[p0 + i];
    int j = (int)(kv & 0xFFFFFFFFull);
    float x = ikey((unsigned int)(kv >> 32));
    unsigned int t = (unsigned int)(row * V) + (unsigned int)j;
    unsigned int bb = tf_bits(t);
    float u = __uint_as_float((bb >> 9) | 0x3f800000u) - 1.0f;
    if (u < TINYF) u = TINYF;
    float g = -logf(-logf(u));
    float sc = x + g;
    if (sc > bs || (sc == bs && j < bi)) { bs = sc; bi = j; }
  }

  // ---- scatter nonzero probs (zeros laid down by kF_zero) ----
  for (int i = tid; i < L; i += 1024) {
    int j = (int)(s_skey[p0 + i] & 0xFFFFFFFFull);
    prow[j] = s_e2[i];
  }

  // ---- argmax reduce -> sampled id ----
#pragma unroll
  for (int d = 32; d > 0; d >>= 1) {
    float ov = __shfl_down(bs, d);
    int oi = __shfl_down(bi, d);
    if (ov > bs || (ov == bs && oi < bi)) { bs = ov; bi = oi; }
  }
  if (lane == 0) { s_wredf[wid] = bs; s_wredi[wid] = bi; }
  bar_lds();
  if (tid == 0) {
    float bb = s_wredf[0];
    int bj = s_wredi[0];
    for (int i = 1; i < 16; ++i) {
      if (s_wredf[i] > bb || (s_wredf[i] == bb && s_wredi[i] < bj)) {
        bb = s_wredf[i];
        bj = s_wredi[i];
      }
    }
    out_ids[row] = (float)bj;
  }
}

// ================== Fallback: monolithic kernel (ws too small) ==================
__global__ __launch_bounds__(1024, 1) void sampler_mono(
    const float* __restrict__ logits, const int* __restrict__ toks,
    const float* __restrict__ temps, const float* __restrict__ topps,
    const int* __restrict__ topks, const float* __restrict__ rps,
    float* __restrict__ out_ids, float* __restrict__ probs) {
  __shared__ unsigned int s_seen[VW];
  __shared__ int s_hist[4096];
  __shared__ unsigned short s_cmax16[NCHUNK];
  __shared__ float s_sval[CAPM];
  __shared__ int s_sidx[CAPM];
  __shared__ float s_e[CAPM];
  __shared__ unsigned char s_keep[CAPM];
  __shared__ float s_wredf[16];
  __shared__ int s_wredi[16];
  __shared__ float s_m, s_denom, s_denom2;
  __shared__ int s_b0, s_cnt, s_p0;

  const int row = blockIdx.x;
  const int tid = threadIdx.x;
  const int lane = tid & 63;
  const int wid = tid >> 6;
  const float rp = rps[row];
  const float irp = 1.0f / rp;
  const float itemp = 1.0f / temps[row];
  const float topp = topps[row];
  const int k = topks[row];
  const size_t base = (size_t)row * V;
  const float4* __restrict__ lg4 = reinterpret_cast<const float4*>(logits + base);
  vfloat4* __restrict__ pr4 = reinterpret_cast<vfloat4*>(probs + base);

  for (int i = tid; i < VW; i += 1024) s_seen[i] = 0u;
  for (int i = tid; i < 4096; i += 1024) s_hist[i] = 0;
  __syncthreads();
  for (int i = tid; i < W; i += 1024) {
    int tok = toks[row * W + i];
    if (tok >= 0 && tok < V) atomicOr(&s_seen[tok >> 5], 1u << (tok & 31));
  }
  __syncthreads();

  float lmax = -INFINITY;
  for (int qb = 0; qb < V4; qb += 1024) {
    const int q = qb + tid;
    unsigned int kmax = 0u;
    if (q < V4) {
      float4 x4 = lg4[q];
      float xs[4] = {x4.x, x4.y, x4.z, x4.w};
      const int j0 = q * 4;
      const int sh = j0 & 31;
      unsigned long long ww = (unsigned long long)s_seen[j0 >> 5] |
                              ((unsigned long long)s_seen[(j0 + 3) >> 5] << 32);
#pragma unroll
      for (int e = 0; e < 4; ++e) {
        float x = xform(xs[e], (ww >> (sh + e)) & 1ull, rp, irp, itemp);
        lmax = fmaxf(lmax, x);
        unsigned int ky = fkey(x);
        kmax = kmax > ky ? kmax : ky;
      }
    }
    unsigned int o;
    o = __shfl_xor(kmax, 1); kmax = kmax > o ? kmax : o;
    o = __shfl_xor(kmax, 2); kmax = kmax > o ? kmax : o;
    if (((lane & 3) == 0) && (q < V4)) s_cmax16[q >> 2] = (unsigned short)(kmax >> 16);
  }
#pragma unroll
  for (int d = 32; d > 0; d >>= 1) lmax = fmaxf(lmax, __shfl_xor(lmax, d));
  if (lane == 0) s_wredf[wid] = lmax;
  __syncthreads();
  for (int i = tid; i < NCHUNK; i += 1024)
    atomicAdd(&s_hist[s_cmax16[i] >> 4], 1);
  __syncthreads();
  if (wid == 1 && lane == 0) {
    float mm = s_wredf[0];
    for (int i = 1; i < 16; ++i) mm = fmaxf(mm, s_wredf[i]);
    s_m = mm;
  }
  if (wid == 0) {
    int sm = 0;
    const int bb = lane * 64;
    for (int i = 0; i < 64; ++i) sm += s_hist[bb + i];
    int sfx = sm;
#pragma unroll
    for (int d = 1; d < 64; d <<= 1) {
      int t = __shfl_down(sfx, d);
      if (lane + d < 64) sfx += t;
    }
    unsigned long long mk = __ballot(sfx >= k);
    const int cstar = 63 - __builtin_clzll(mk);
    const int above = __shfl(sfx, cstar) - __shfl(sm, cstar);
    int h = s_hist[cstar * 64 + lane];
    int sfx2 = h;
#pragma unroll
    for (int d = 1; d < 64; d <<= 1) {
      int t = __shfl_down(sfx2, d);
      if (lane + d < 64) sfx2 += t;
    }
    unsigned long long mk2 = __ballot(above + sfx2 >= k);
    const int boff = 63 - __builtin_clzll(mk2);
    if (lane == 0) { s_b0 = cstar * 64 + boff; s_cnt = 0; }
  }
  __syncthreads();
  const int b0 = s_b0;
  const unsigned int fk0 = ((unsigned int)b0) << 20;
  const int c16 = b0 << 4;
  for (int qb = 0; qb < V4; qb += 1024) {
    const int q = qb + tid;
    const bool act = (q < V4) && ((int)s_cmax16[q >> 2] >= c16);
    float xs[4];
    bool pr[4] = {false, false, false, false};
    const int j0 = q * 4;
    if (act) {
      float4 x4 = lg4[q];
      float raw[4] = {x4.x, x4.y, x4.z, x4.w};
      const int sh = j0 & 31;
      unsigned long long ww = (unsigned long long)s_seen[j0 >> 5] |
                              ((unsigned long long)s_seen[(j0 + 3) >> 5] << 32);
#pragma unroll
      for (int e = 0; e < 4; ++e) {
        xs[e] = xform(raw[e], (ww >> (sh + e)) & 1ull, rp, irp, itemp);
        pr[e] = (fkey(xs[e]) >= fk0);
      }
    }
#pragma unroll
    for (int e = 0; e < 4; ++e) {
      unsigned long long mask = __ballot(pr[e]);
      if (!mask) continue;
      int basep = 0;
      if (lane == 0) basep = atomicAdd(&s_cnt, __popcll(mask));
      basep = __shfl(basep, 0);
      if (pr[e]) {
        int pos = basep + __popcll(mask & ((1ull << lane) - 1ull));
        if (pos < CAPM) { s_sval[pos] = xs[e]; s_sidx[pos] = j0 + e; }
      }
    }
  }
  __syncthreads();
  int G = s_cnt;
  if (G > CAPM) G = CAPM;
  int np2 = 2;
  while (np2 < G) np2 <<= 1;
  for (int i = G + tid; i < np2; i += 1024) {
    s_sval[i] = INFINITY;
    s_sidx[i] = 0x7FFFFFFF;
  }
  __syncthreads();
  for (int size = 2; size <= np2; size <<= 1) {
    for (int stride = size >> 1; stride > 0; stride >>= 1) {
      for (int t2 = tid; t2 < (np2 >> 1); t2 += 1024) {
        int pos = 2 * t2 - (t2 & (stride - 1));
        int qq = pos + stride;
        bool up = ((pos & size) == 0);
        float v1 = s_sval[pos], v2 = s_sval[qq];
        int i1 = s_sidx[pos], i2 = s_sidx[qq];
        bool gt = (v1 > v2) || (v1 == v2 && i1 > i2);
        if (gt == up) {
          s_sval[pos] = v2; s_sval[qq] = v1;
          s_sidx[pos] = i2; s_sidx[qq] = i1;
        }
      }
      __syncthreads();
    }
  }
  const int kk = k > G ? G : k;
  const float kth = s_sval[G - kk];
  const float m = s_m;
  for (int i = tid; i < G; i += 1024) {
    if (s_sval[i] >= kth && (i == 0 || s_sval[i - 1] < kth)) s_p0 = i;
  }
  __syncthreads();
  const int p0 = s_p0;
  float part = 0.0f;
  for (int i = p0 + tid; i < G; i += 1024) {
    float e = expf(s_sval[i] - m);
    s_e[i] = e;
    part += e;
  }
#pragma unroll
  for (int d = 32; d > 0; d >>= 1) part += __shfl_xor(part, d);
  if (lane == 0) s_wredf[wid] = part;
  __syncthreads();
  if (tid == 0) {
    float s = 0.0f;
    for (int i = 0; i < 16; ++i) s += s_wredf[i];
    s_denom = s;
  }
  __syncthreads();
  const float denom = s_denom;
  if (tid == 0) {
    const float cut = 1.0f - topp;
    float cs = 0.0f;
    for (int i = p0; i < G; ++i) {
      cs += s_e[i] / denom;
      s_keep[i] = (cs <= cut) ? 0 : 1;
    }
    s_keep[G - 1] = 1;
  }
  __syncthreads();
  part = 0.0f;
  for (int i = p0 + tid; i < G; i += 1024)
    if (s_keep[i]) part += s_e[i];
#pragma unroll
  for (int d = 32; d > 0; d >>= 1) part += __shfl_xor(part, d);
  if (lane == 0) s_wredf[wid] = part;
  __syncthreads();
  if (tid == 0) {
    float s = 0.0f;
    for (int i = 0; i < 16; ++i) s += s_wredf[i];
    s_denom2 = s;
  }
  __syncthreads();
  const float denom2 = s_denom2;
  for (int i = p0 + tid; i < G; i += 1024)
    s_e[i] = s_keep[i] ? (s_e[i] / denom2) : 0.0f;
  __syncthreads();
  float bs = -INFINITY;
  int bi = 0x7FFFFFFF;
  for (int i = p0 + tid; i < G; i += 1024) {
    if (!s_keep[i]) continue;
    int j = s_sidx[i];
    unsigned int t = (unsigned int)(row * V) + (unsigned int)j;
    unsigned int bb = tf_bits(t);
    float u = __uint_as_float((bb >> 9) | 0x3f800000u) - 1.0f;
    if (u < TINYF) u = TINYF;
    float g = -logf(-logf(u));
    float sc = s_sval[i] + g;
    if (sc > bs || (sc == bs && j < bi)) { bs = sc; bi = j; }
  }
  const unsigned int kkey = fkey(kth);
  const int k16 = (int)(kkey >> 16);
  for (int q = tid; q < V4; q += 1024) {
    vfloat4 o = (vfloat4){0.0f, 0.0f, 0.0f, 0.0f};
    if ((int)s_cmax16[q >> 2] >= k16) {
      float4 x4 = lg4[q];
      float raw[4] = {x4.x, x4.y, x4.z, x4.w};
      float os[4];
      const int j0 = q * 4;
      const int sh = j0 & 31;
      unsigned long long ww = (unsigned long long)s_seen[j0 >> 5] |
                              ((unsigned long long)s_seen[(j0 + 3) >> 5] << 32);
#pragma unroll
      for (int e = 0; e < 4; ++e) {
        float x = xform(raw[e], (ww >> (sh + e)) & 1ull, rp, irp, itemp);
        float pr = 0.0f;
        if (x >= kth) {
          int j = j0 + e;
          int lo = p0, hi = G;
          while (lo < hi) {
            int mid = (lo + hi) >> 1;
            float v = s_sval[mid];
            int id = s_sidx[mid];
            if (v < x || (v == x && id < j)) lo = mid + 1; else hi = mid;
          }
          pr = s_e[lo];
        }
        os[e] = pr;
      }
      o.x = os[0]; o.y = os[1]; o.z = os[2]; o.w = os[3];
    }
    pr4[q] = o;
  }
#pragma unroll
  for (int d = 32; d > 0; d >>= 1) {
    float ov = __shfl_down(bs, d);
    int oi = __shfl_down(bi, d);
    if (ov > bs || (ov == bs && oi < bi)) { bs = ov; bi = oi; }
  }
  if (lane == 0) { s_wredf[wid] = bs; s_wredi[wid] = bi; }
  __syncthreads();
  if (tid == 0) {
    float bb = s_wredf[0];
    int bj = s_wredi[0];
    for (int i = 1; i < 16; ++i) {
      if (s_wredf[i] > bb || (s_wredf[i] == bb && s_wredi[i] < bj)) {
        bb = s_wredf[i];
        bj = s_wredi[i];
      }
    }
    out_ids[row] = (float)bj;
  }
}

extern "C" void kernel_launch(void* const* d_in, const int* in_sizes, int n_in,
                              void* d_out, int out_size, void* d_ws, size_t ws_size,
                              hipStream_t stream) {
  (void)in_sizes; (void)out_size;
  if (n_in < 6) return;
  const float* logits = (const float*)d_in[0];
  const int* toks = (const int*)d_in[1];
  const float* temps = (const float*)d_in[2];
  const float* topps = (const float*)d_in[3];
  const int* topks = (const int*)d_in[4];
  const float* rps = (const float*)d_in[5];
  float* out = (float*)d_out;            // [0,256): ids as float; [256,...): probs
  float* probs = out + NROWS;

  if (ws_size >= WS_NEED && d_ws != nullptr) {
    char* w = (char*)d_ws;
    unsigned short* ws_cmax = (unsigned short*)(w + WS_CMAX);
    float* ws_bmax = (float*)(w + WS_BMAX);
    int* ws_b0 = (int*)(w + WS_B0);
    int* ws_cnt = (int*)(w + WS_CNT);
    unsigned long long* ws_keys = (unsigned long long*)(w + WS_KEYS);
    kF_zero<<<dim3(2048), dim3(256), 0, stream>>>(probs);
    kA_chunkmax<<<dim3(NROWS * NSLICE), dim3(256), 0, stream>>>(
        logits, toks, temps, rps, ws_cmax, ws_bmax);
    kS_b0<<<dim3(NROWS), dim3(1024), 0, stream>>>(ws_cmax, topks, ws_b0, ws_cnt);
    kB1_gather<<<dim3(NROWS * NSLICE), dim3(256), 0, stream>>>(
        logits, toks, temps, rps, ws_cmax, ws_b0, ws_cnt, ws_keys);
    kB2_finish<<<dim3(NROWS), dim3(1024), 0, stream>>>(
        topps, topks, ws_bmax, ws_cnt, ws_keys, out, probs);
  } else {
    sampler_mono<<<dim3(NROWS), dim3(1024), 0, stream>>>(
        logits, toks, temps, topps, topks, rps, out, probs);
  }
}

// Round 16
// 127.273 us; speedup vs baseline: 1.6154x; 1.6154x over previous
//
#include <hip/hip_runtime.h>

#define V 128000
#define V4 (V / 4)
#define NROWS 256
#define V4ALL (NROWS * V4)
#define NCHUNK (V / 16)      // 8000 chunk-max entries
#define NSLICE 8
#define SL4 (V4 / NSLICE)    // 4000 float4 per slice
#define SLC (NCHUNK / NSLICE)// 1000 chunks per slice
#define W 200
#define VW (V / 32)
#define CAP 4096             // candidate capacity
#define CAPS 2048            // survivor capacity
#define CAPM 8192            // mono-kernel capacity
#define TINYF 1.17549435e-38f
#define HIDX(b) ((b) + ((b) >> 5))
#define HSZ 4224

// ---- d_ws layout ----
#define WS_CMAX   0u          // u16[256][8000] = 4,096,000
#define WS_BMAX   4104192u    // float[256][8]
#define WS_B0     4112384u    // int[256]
#define WS_CNT    4113408u    // int[256]
#define WS_KEYS   8388608u    // u64[256][4096] = 8 MiB
#define WS_NEED   16777216u

typedef float vfloat4 __attribute__((ext_vector_type(4)));

__device__ __forceinline__ void bar_lds() {
  asm volatile("s_waitcnt lgkmcnt(0)" ::: "memory");
  __builtin_amdgcn_s_barrier();
}

__device__ __forceinline__ unsigned int fkey(float x) {
  unsigned int u = __float_as_uint(x);
  return (u & 0x80000000u) ? ~u : (u | 0x80000000u);
}
__device__ __forceinline__ float ikey(unsigned int k) {
  unsigned int u = (k & 0x80000000u) ? (k & 0x7FFFFFFFu) : ~k;
  return __uint_as_float(u);
}

// ---- jax threefry2x32, partitionable: counter=(0,t), key=(0,42), fold=xor ----
__device__ __forceinline__ unsigned int tf_bits(unsigned int t) {
  const unsigned int k0 = 0u, k1 = 42u;
  const unsigned int ks2 = k0 ^ k1 ^ 0x1BD11BDAu;
  unsigned int x0 = 0u + k0, x1 = t + k1;
  const unsigned int ksArr[3] = {k0, k1, ks2};
  const int RA[4] = {13, 15, 26, 6};
  const int RB[4] = {17, 29, 16, 24};
#pragma unroll
  for (int i = 0; i < 5; ++i) {
#pragma unroll
    for (int j = 0; j < 4; ++j) {
      int r = (i & 1) ? RB[j] : RA[j];
      x0 += x1;
      x1 = (x1 << r) | (x1 >> (32 - r));
      x1 ^= x0;
    }
    x0 += ksArr[(i + 1) % 3];
    x1 += ksArr[(i + 2) % 3] + (unsigned int)(i + 1);
  }
  return x0 ^ x1;
}

__device__ __forceinline__ float xform(float x, bool seen, float rp, float irp,
                                        float itemp) {
  if (seen) x = (x > 0.0f) ? x * irp : x * rp;
  return x * itemp;
}

// Wave-parallel suffix select over a padded 4096-bucket histogram (one wave).
__device__ __forceinline__ void wave_suffix_select_p(const int* hist, int need,
                                                     int lane, int* out_b,
                                                     int* out_rem) {
  int sm = 0;
  const int bb = lane * 64;
  for (int i = 0; i < 64; ++i) sm += hist[HIDX(bb + i)];
  int sfx = sm;
#pragma unroll
  for (int d = 1; d < 64; d <<= 1) {
    int t = __shfl_down(sfx, d);
    if (lane + d < 64) sfx += t;
  }
  unsigned long long mk = __ballot(sfx >= need);
  const int cstar = 63 - __builtin_clzll(mk);
  const int aboveC = __shfl(sfx, cstar) - __shfl(sm, cstar);
  int h = hist[HIDX(cstar * 64 + lane)];
  int sfx2 = h;
#pragma unroll
  for (int d = 1; d < 64; d <<= 1) {
    int t = __shfl_down(sfx2, d);
    if (lane + d < 64) sfx2 += t;
  }
  unsigned long long mk2 = __ballot(aboveC + sfx2 >= need);
  const int boff = 63 - __builtin_clzll(mk2);
  const int aboveB = aboveC + __shfl(sfx2, boff) - __shfl(h, boff);
  if (lane == 0) {
    *out_b = cstar * 64 + boff;
    *out_rem = need - aboveB;
  }
}

// ====== Kernel F: zero-fill probs at full write bandwidth ======
__global__ __launch_bounds__(256) void kF_zero(float* __restrict__ probs) {
  vfloat4* __restrict__ p4 = reinterpret_cast<vfloat4*>(probs);
  const vfloat4 z4 = (vfloat4){0.0f, 0.0f, 0.0f, 0.0f};
  const int stride = gridDim.x * 256;
  for (int q = blockIdx.x * 256 + threadIdx.x; q < V4ALL; q += stride)
    p4[q] = z4;
}

// ====== Kernel A: transform + chunk-max + slice-max (pure read) ======
__global__ __launch_bounds__(256) void kA_chunkmax(
    const float* __restrict__ logits, const int* __restrict__ toks,
    const float* __restrict__ temps, const float* __restrict__ rps,
    unsigned short* __restrict__ ws_cmax, float* __restrict__ ws_bmax) {
  __shared__ unsigned int s_seen[VW];
  __shared__ float s_red[4];
  const int row = blockIdx.x >> 3;
  const int slice = blockIdx.x & 7;
  const int tid = threadIdx.x;
  const int lane = tid & 63;
  const int wid = tid >> 6;
  const float rp = rps[row];
  const float irp = 1.0f / rp;
  const float itemp = 1.0f / temps[row];
  const size_t base = (size_t)row * V;
  const float4* __restrict__ lg4 = reinterpret_cast<const float4*>(logits + base);

  for (int i = tid; i < VW; i += 256) s_seen[i] = 0u;
  __syncthreads();
  for (int i = tid; i < W; i += 256) {
    int tok = toks[row * W + i];
    if (tok >= 0 && tok < V) atomicOr(&s_seen[tok >> 5], 1u << (tok & 31));
  }
  __syncthreads();

  float lmax = -INFINITY;
  const int q0 = slice * SL4;
  for (int qi = tid; qi < SL4; qi += 256) {
    const int q = q0 + qi;
    float4 x4 = lg4[q];
    float xs[4] = {x4.x, x4.y, x4.z, x4.w};
    const int j0 = q * 4;
    const int sh = j0 & 31;
    unsigned long long ww = (unsigned long long)s_seen[j0 >> 5] |
                            ((unsigned long long)s_seen[(j0 + 3) >> 5] << 32);
    unsigned int kmax = 0u;
#pragma unroll
    for (int e = 0; e < 4; ++e) {
      float x = xform(xs[e], (ww >> (sh + e)) & 1ull, rp, irp, itemp);
      lmax = fmaxf(lmax, x);
      unsigned int ky = fkey(x);
      kmax = kmax > ky ? kmax : ky;
    }
    unsigned int o;
    o = __shfl_xor(kmax, 1); kmax = kmax > o ? kmax : o;
    o = __shfl_xor(kmax, 2); kmax = kmax > o ? kmax : o;
    if ((lane & 3) == 0) ws_cmax[row * NCHUNK + (q >> 2)] = (unsigned short)(kmax >> 16);
  }
#pragma unroll
  for (int d = 32; d > 0; d >>= 1) lmax = fmaxf(lmax, __shfl_xor(lmax, d));
  if (lane == 0) s_red[wid] = lmax;
  __syncthreads();
  if (tid == 0) {
    float mm = fmaxf(fmaxf(s_red[0], s_red[1]), fmaxf(s_red[2], s_red[3]));
    ws_bmax[row * NSLICE + slice] = mm;
  }
}

// ====== Kernel S: per-row b0 select from chunk-max histogram (4x replicated) ======
__global__ __launch_bounds__(1024) void kS_b0(
    const unsigned short* __restrict__ ws_cmax, const int* __restrict__ topks,
    int* __restrict__ ws_b0, int* __restrict__ ws_cnt) {
  __shared__ int s_h[4 * HSZ];   // 67.6 KB
  __shared__ int s_b, s_rem;
  const int row = blockIdx.x;
  const int tid = threadIdx.x;
  const int lane = tid & 63;
  const int wid = tid >> 6;
  for (int i = tid; i < 4 * HSZ; i += 1024) s_h[i] = 0;
  __syncthreads();
  const unsigned short* cm = ws_cmax + row * NCHUNK;
  const int rep = (tid & 3) * HSZ;
  for (int i = tid; i < NCHUNK; i += 1024)
    atomicAdd(&s_h[rep + HIDX(cm[i] >> 4)], 1);
  __syncthreads();
  for (int i = tid; i < HSZ; i += 1024)
    s_h[i] += s_h[i + HSZ] + s_h[i + 2 * HSZ] + s_h[i + 3 * HSZ];
  __syncthreads();
  if (wid == 0) wave_suffix_select_p(s_h, topks[row], lane, &s_b, &s_rem);
  __syncthreads();
  if (tid == 0) {
    ws_b0[row] = s_b;
    ws_cnt[row] = 0;
  }
}

// ====== Kernel B1: two-pass gather — ONE global atomic per block ======
// Pass 1 counts candidates per wave (registers only); thread 0 does a single
// atomicAdd to ws_cnt[row]; pass 2 recomputes and scatters to the reserved
// range. Wave-wide shuffles stay uniform (uniform-trip loops).
__global__ __launch_bounds__(256) void kB1_gather(
    const float* __restrict__ logits, const int* __restrict__ toks,
    const float* __restrict__ temps, const float* __restrict__ rps,
    const unsigned short* __restrict__ ws_cmax, const int* __restrict__ ws_b0,
    int* __restrict__ ws_cnt, unsigned long long* __restrict__ ws_keys) {
  __shared__ unsigned int s_seen[VW];     // 16 KB
  __shared__ unsigned short s_cm[SLC];    // 2 KB
  __shared__ int s_wq[4];
  const int row = blockIdx.x >> 3;
  const int slice = blockIdx.x & 7;
  const int tid = threadIdx.x;
  const int lane = tid & 63;
  const int wid = tid >> 6;
  const float rp = rps[row];
  const float irp = 1.0f / rp;
  const float itemp = 1.0f / temps[row];
  const size_t base = (size_t)row * V;
  const float4* __restrict__ lg4 = reinterpret_cast<const float4*>(logits + base);

  for (int i = tid; i < VW; i += 256) s_seen[i] = 0u;
  for (int i = tid; i < SLC; i += 256)
    s_cm[i] = ws_cmax[row * NCHUNK + slice * SLC + i];
  __syncthreads();
  for (int i = tid; i < W; i += 256) {
    int tok = toks[row * W + i];
    if (tok >= 0 && tok < V) atomicOr(&s_seen[tok >> 5], 1u << (tok & 31));
  }
  __syncthreads();

  const int b0 = ws_b0[row];
  const unsigned int fk0 = ((unsigned int)b0) << 20;
  const int c16 = b0 << 4;
  unsigned long long* __restrict__ krow = ws_keys + (size_t)row * CAP;
  const int q0 = slice * SL4;

  // ---- pass 1: per-wave candidate count (no stores) ----
  int wcnt = 0;
  for (int qb = 0; qb < SL4; qb += 256) {
    const int qi = qb + tid;
    const bool inb = (qi < SL4);
    const bool act = inb && ((int)s_cm[qi >> 2] >= c16);
    if (act) {
      const int q = q0 + qi;
      float4 x4 = lg4[q];
      float raw[4] = {x4.x, x4.y, x4.z, x4.w};
      const int j0 = q * 4;
      const int sh = j0 & 31;
      unsigned long long ww = (unsigned long long)s_seen[j0 >> 5] |
                              ((unsigned long long)s_seen[(j0 + 3) >> 5] << 32);
#pragma unroll
      for (int e = 0; e < 4; ++e) {
        float x = xform(raw[e], (ww >> (sh + e)) & 1ull, rp, irp, itemp);
        wcnt += (int)(fkey(x) >= fk0);
      }
    }
  }
#pragma unroll
  for (int d = 32; d > 0; d >>= 1) wcnt += __shfl_xor(wcnt, d);
  if (lane == 0) s_wq[wid] = wcnt;
  __syncthreads();
  if (tid == 0) {
    int t0 = s_wq[0], t1 = s_wq[1], t2 = s_wq[2], t3 = s_wq[3];
    int tot = t0 + t1 + t2 + t3;
    int basep = tot ? atomicAdd(&ws_cnt[row], tot) : 0;
    s_wq[0] = basep;
    s_wq[1] = basep + t0;
    s_wq[2] = basep + t0 + t1;
    s_wq[3] = basep + t0 + t1 + t2;
  }
  __syncthreads();
  int wbase = s_wq[wid];

  // ---- pass 2: recompute + scatter into reserved range ----
  for (int qb = 0; qb < SL4; qb += 256) {
    const int qi = qb + tid;
    const bool inb = (qi < SL4);
    const bool act = inb && ((int)s_cm[qi >> 2] >= c16);
    const int q = q0 + qi;
    const int j0 = q * 4;
    unsigned int ks[4];
    bool pr[4] = {false, false, false, false};
    if (act) {
      float4 x4 = lg4[q];
      float raw[4] = {x4.x, x4.y, x4.z, x4.w};
      const int sh = j0 & 31;
      unsigned long long ww = (unsigned long long)s_seen[j0 >> 5] |
                              ((unsigned long long)s_seen[(j0 + 3) >> 5] << 32);
#pragma unroll
      for (int e = 0; e < 4; ++e) {
        float x = xform(raw[e], (ww >> (sh + e)) & 1ull, rp, irp, itemp);
        ks[e] = fkey(x);
        pr[e] = (ks[e] >= fk0);
      }
    }
    int cnt = (int)pr[0] + (int)pr[1] + (int)pr[2] + (int)pr[3];
    int inc = cnt;
#pragma unroll
    for (int d = 1; d < 64; d <<= 1) {
      int t = __shfl_up(inc, d);
      if (lane >= d) inc += t;
    }
    const int total = __shfl(inc, 63);
    if (total) {
      int off = wbase + inc - cnt;
#pragma unroll
      for (int e = 0; e < 4; ++e) {
        if (pr[e]) {
          if (off < CAP)
            krow[off] = ((unsigned long long)ks[e] << 32) | (unsigned int)(j0 + e);
          ++off;
        }
      }
      wbase += total;
    }
  }
}

// ====== Kernel B2: radix-kth + compact + counting sort + top-p + sample + scatter ======
__global__ __launch_bounds__(1024) void kB2_finish(
    const float* __restrict__ topps, const int* __restrict__ topks,
    const float* __restrict__ ws_bmax, const int* __restrict__ ws_cnt,
    const unsigned long long* __restrict__ ws_keys,
    float* __restrict__ out_ids, float* __restrict__ probs) {
  __shared__ unsigned long long s_key[CAP];             // 32 KB: keys; later sorted+overlays
  __shared__ __align__(16) int s_h[4 * HSZ];            // 67.6 KB: replicated hists -> keep
  __shared__ __align__(16) unsigned char s_bufB[16384]; // 16 KB: survivors (unsorted)
  __shared__ float s_wredf[16];
  __shared__ int s_wredi[16];
  __shared__ float s_mv, s_dn1, s_dn2;
  __shared__ int s_scnt, s_selb, s_selrem, s_p0v, s_maxpop;

  unsigned long long* s_key2 = (unsigned long long*)s_bufB;
  unsigned long long* s_skey = s_key;
  float* s_e2 = (float*)(s_key + CAPS);
  float* s_q2 = (float*)(s_key + CAPS + CAPS / 2);
  unsigned char* s_keep = (unsigned char*)s_h;          // overlay (hists dead post-sort)

  const int row = blockIdx.x;
  const int tid = threadIdx.x;
  const int lane = tid & 63;
  const int wid = tid >> 6;
  const float topp = topps[row];
  const int k = topks[row];
  float* __restrict__ prow = probs + (size_t)row * V;

  int G = ws_cnt[row];
  if (G > CAP) G = CAP;
  const int kk = k > G ? G : k;
  {
    const unsigned long long* krow = ws_keys + (size_t)row * CAP;
    for (int i = tid; i < G; i += 1024) s_key[i] = krow[i];
  }
  if (wid == 1 && lane == 0) {
    float mm = ws_bmax[row * NSLICE];
    for (int i = 1; i < NSLICE; ++i) mm = fmaxf(mm, ws_bmax[row * NSLICE + i]);
    s_mv = mm;
  }
  for (int i = tid; i < 4 * HSZ; i += 1024) s_h[i] = 0;
  __syncthreads();

  // ---- 1-pass radix (replicated): bucket (fkey>>20) of the kk-th largest ----
  const int rep = (tid & 3) * HSZ;
  for (int i = tid; i < G; i += 1024)
    atomicAdd(&s_h[rep + HIDX((unsigned int)(s_key[i] >> 52))], 1);
  bar_lds();
  for (int i = tid; i < HSZ; i += 1024)
    s_h[i] += s_h[i + HSZ] + s_h[i + 2 * HSZ] + s_h[i + 3 * HSZ];
  bar_lds();
  if (wid == 0) {
    wave_suffix_select_p(s_h, kk, lane, &s_selb, &s_selrem);
    if (lane == 0) s_scnt = 0;
  }
  bar_lds();
  const unsigned int b1 = (unsigned int)s_selb;

  // ---- compact survivor-superset (top12 >= b1) into s_key2 ----
  for (int ib = 0; ib < G; ib += 1024) {
    const int i = ib + tid;
    const bool p = (i < G) && ((unsigned int)(s_key[i] >> 52) >= b1);
    unsigned long long mask = __ballot(p);
    if (!mask) continue;
    int basep = 0;
    if (lane == 0) basep = atomicAdd(&s_scnt, __popcll(mask));
    basep = __shfl(basep, 0);
    if (p) {
      int pos = basep + __popcll(mask & ((1ull << lane) - 1ull));
      if (pos < CAPS) s_key2[pos] = s_key[i];
    }
  }
  bar_lds();
  int S = s_scnt;
  if (S > CAPS) S = CAPS;
  const float m = s_mv;

  // ---- counting sort by value bins (replicated counts), bitonic fallback ----
  const unsigned int cbase = b1 << 20;
  const unsigned int span = fkey(m) - cbase;
  int shiftb;
  {
    int bits = 32 - __clz((int)(span | 1u));
    shiftb = bits > 12 ? bits - 12 : 0;
  }
  for (int i = tid; i < 4 * HSZ; i += 1024) s_h[i] = 0;
  bar_lds();
  for (int i = tid; i < S; i += 1024) {
    unsigned int hi = (unsigned int)(s_key2[i] >> 32);
    int b = (int)((hi - cbase) >> shiftb);
    if (b > 4095) b = 4095;
    atomicAdd(&s_h[rep + HIDX(b)], 1);
  }
  bar_lds();
  for (int i = tid; i < HSZ; i += 1024)
    s_h[i] += s_h[i + HSZ] + s_h[i + 2 * HSZ] + s_h[i + 3 * HSZ];
  bar_lds();
  if (wid == 0) {
    int T = 0, mx = 0;
    const int bb = lane * 64;
    for (int i = 0; i < 64; ++i) {
      int c = s_h[HIDX(bb + i)];
      T += c;
      mx = c > mx ? c : mx;
    }
    int ex = T;
#pragma unroll
    for (int d = 1; d < 64; d <<= 1) {
      int t = __shfl_up(ex, d);
      if (lane >= d) ex += t;
    }
    ex -= T;
    int run = ex;
    for (int i = 0; i < 64; ++i) {
      int idx = HIDX(bb + i);
      int c = s_h[idx];
      s_h[idx] = run;
      run += c;
    }
#pragma unroll
    for (int d = 32; d > 0; d >>= 1) {
      int o = __shfl_xor(mx, d);
      mx = o > mx ? o : mx;
    }
    if (lane == 0) s_maxpop = mx;
  }
  bar_lds();

  if (s_maxpop <= 16) {
    for (int i = tid; i < S; i += 1024) {
      unsigned long long key = s_key2[i];
      unsigned int hi = (unsigned int)(key >> 32);
      int b = (int)((hi - cbase) >> shiftb);
      if (b > 4095) b = 4095;
      int pos = atomicAdd(&s_h[HIDX(b)], 1);
      s_skey[pos] = key;
    }
    bar_lds();
    for (int b = tid; b < 4096; b += 1024) {
      int endb = s_h[HIDX(b)];
      int st = (b == 0) ? 0 : s_h[HIDX(b - 1)];
      for (int i = st + 1; i < endb; ++i) {
        unsigned long long key = s_skey[i];
        int j = i - 1;
        while (j >= st && s_skey[j] > key) {
          s_skey[j + 1] = s_skey[j];
          --j;
        }
        s_skey[j + 1] = key;
      }
    }
    bar_lds();
  } else {
    int np2 = 2;
    while (np2 < S) np2 <<= 1;
    for (int i = S + tid; i < np2; i += 1024) s_key2[i] = ~0ull;
    bar_lds();
    for (int size = 2; size <= np2; size <<= 1) {
      for (int stride = size >> 1; stride > 0; stride >>= 1) {
        for (int t2 = tid; t2 < (np2 >> 1); t2 += 1024) {
          int pos = 2 * t2 - (t2 & (stride - 1));
          int qq = pos + stride;
          bool up = ((pos & size) == 0);
          unsigned long long a = s_key2[pos], b = s_key2[qq];
          if ((a > b) == up) { s_key2[pos] = b; s_key2[qq] = a; }
        }
        bar_lds();
      }
    }
    for (int i = tid; i < S; i += 1024) s_skey[i] = s_key2[i];
    bar_lds();
  }

  // ---- exact kth + survivor range [p0, S) ----
  const unsigned int kthkey32 = (unsigned int)(s_skey[S - kk] >> 32);
  for (int i = tid; i < S; i += 1024) {
    unsigned int hi = (unsigned int)(s_skey[i] >> 32);
    if (hi >= kthkey32 && (i == 0 || (unsigned int)(s_skey[i - 1] >> 32) < kthkey32))
      s_p0v = i;
  }
  bar_lds();
  const int p0 = s_p0v;
  const int L = S - p0;

  // ---- softmax denom over survivors ----
  float part = 0.0f;
  for (int i = tid; i < L; i += 1024) {
    float x = ikey((unsigned int)(s_skey[p0 + i] >> 32));
    float e = expf(x - m);
    s_e2[i] = e;
    part += e;
  }
#pragma unroll
  for (int d = 32; d > 0; d >>= 1) part += __shfl_xor(part, d);
  if (lane == 0) s_wredf[wid] = part;
  bar_lds();
  if (tid == 0) {
    float s = 0.0f;
    for (int i = 0; i < 16; ++i) s += s_wredf[i];
    s_dn1 = s;
  }
  bar_lds();
  const float denom = s_dn1;

  for (int i = tid; i < L; i += 1024) s_q2[i] = s_e2[i] / denom;
  bar_lds();

  // ---- serial fp32 cumsum (pure add chain) + top-p mask, last kept ----
  if (tid == 0) {
    const float cut = 1.0f - topp;
    float cs = 0.0f;
    int i = 0;
    for (; i + 16 <= L; i += 16) {
      vfloat4 a = *(const vfloat4*)&s_q2[i];
      vfloat4 b = *(const vfloat4*)&s_q2[i + 4];
      vfloat4 c = *(const vfloat4*)&s_q2[i + 8];
      vfloat4 d = *(const vfloat4*)&s_q2[i + 12];
      unsigned int w0, w1, w2, w3;
      cs += a.x; w0  = (cs <= cut) ? 0u : 1u;
      cs += a.y; w0 |= ((cs <= cut) ? 0u : 1u) << 8;
      cs += a.z; w0 |= ((cs <= cut) ? 0u : 1u) << 16;
      cs += a.w; w0 |= ((cs <= cut) ? 0u : 1u) << 24;
      cs += b.x; w1  = (cs <= cut) ? 0u : 1u;
      cs += b.y; w1 |= ((cs <= cut) ? 0u : 1u) << 8;
      cs += b.z; w1 |= ((cs <= cut) ? 0u : 1u) << 16;
      cs += b.w; w1 |= ((cs <= cut) ? 0u : 1u) << 24;
      cs += c.x; w2  = (cs <= cut) ? 0u : 1u;
      cs += c.y; w2 |= ((cs <= cut) ? 0u : 1u) << 8;
      cs += c.z; w2 |= ((cs <= cut) ? 0u : 1u) << 16;
      cs += c.w; w2 |= ((cs <= cut) ? 0u : 1u) << 24;
      cs += d.x; w3  = (cs <= cut) ? 0u : 1u;
      cs += d.y; w3 |= ((cs <= cut) ? 0u : 1u) << 8;
      cs += d.z; w3 |= ((cs <= cut) ? 0u : 1u) << 16;
      cs += d.w; w3 |= ((cs <= cut) ? 0u : 1u) << 24;
      *(unsigned int*)&s_keep[i] = w0;
      *(unsigned int*)&s_keep[i + 4] = w1;
      *(unsigned int*)&s_keep[i + 8] = w2;
      *(unsigned int*)&s_keep[i + 12] = w3;
    }
    for (; i < L; ++i) {
      cs += s_q2[i];
      s_keep[i] = (cs <= cut) ? 0 : 1;
    }
    s_keep[L - 1] = 1;
  }
  bar_lds();

  // ---- final denom over kept ----
  part = 0.0f;
  for (int i = tid; i < L; i += 1024)
    if (s_keep[i]) part += s_e2[i];
#pragma unroll
  for (int d = 32; d > 0; d >>= 1) part += __shfl_xor(part, d);
  if (lane == 0) s_wredf[wid] = part;
  bar_lds();
  if (tid == 0) {
    float s = 0.0f;
    for (int i = 0; i < 16; ++i) s += s_wredf[i];
    s_dn2 = s;
  }
  bar_lds();
  const float denom2 = s_dn2;

  for (int i = tid; i < L; i += 1024)
    s_e2[i] = s_keep[i] ? (s_e2[i] / denom2) : 0.0f;
  bar_lds();

  // ---- Gumbel argmax over kept survivors ----
  float bs = -INFINITY;
  int bi = 0x7FFFFFFF;
  for (int i = tid; i < L; i += 1024) {
    if (!s_keep[i]) continue;
    unsigned long long kv = s_skey[p0 + i];
    int j = (int)(kv & 0xFFFFFFFFull);
    float x = ikey((unsigned int)(kv >> 32));
    unsigned int t = (unsigned int)(row * V) + (unsigned int)j;
    unsigned int bb = tf_bits(t);
    float u = __uint_as_float((bb >> 9) | 0x3f800000u) - 1.0f;
    if (u < TINYF) u = TINYF;
    float g = -logf(-logf(u));
    float sc = x + g;
    if (sc > bs || (sc == bs && j < bi)) { bs = sc; bi = j; }
  }

  // ---- scatter nonzero probs (zeros laid down by kF_zero) ----
  for (int i = tid; i < L; i += 1024) {
    int j = (int)(s_skey[p0 + i] & 0xFFFFFFFFull);
    prow[j] = s_e2[i];
  }

  // ---- argmax reduce -> sampled id ----
#pragma unroll
  for (int d = 32; d > 0; d >>= 1) {
    float ov = __shfl_down(bs, d);
    int oi = __shfl_down(bi, d);
    if (ov > bs || (ov == bs && oi < bi)) { bs = ov; bi = oi; }
  }
  if (lane == 0) { s_wredf[wid] = bs; s_wredi[wid] = bi; }
  bar_lds();
  if (tid == 0) {
    float bb = s_wredf[0];
    int bj = s_wredi[0];
    for (int i = 1; i < 16; ++i) {
      if (s_wredf[i] > bb || (s_wredf[i] == bb && s_wredi[i] < bj)) {
        bb = s_wredf[i];
        bj = s_wredi[i];
      }
    }
    out_ids[row] = (float)bj;
  }
}

// ================== Fallback: monolithic kernel (ws too small) ==================
__global__ __launch_bounds__(1024, 1) void sampler_mono(
    const float* __restrict__ logits, const int* __restrict__ toks,
    const float* __restrict__ temps, const float* __restrict__ topps,
    const int* __restrict__ topks, const float* __restrict__ rps,
    float* __restrict__ out_ids, float* __restrict__ probs) {
  __shared__ unsigned int s_seen[VW];
  __shared__ int s_hist[4096];
  __shared__ unsigned short s_cmax16[NCHUNK];
  __shared__ float s_sval[CAPM];
  __shared__ int s_sidx[CAPM];
  __shared__ float s_e[CAPM];
  __shared__ unsigned char s_keep[CAPM];
  __shared__ float s_wredf[16];
  __shared__ int s_wredi[16];
  __shared__ float s_m, s_denom, s_denom2;
  __shared__ int s_b0, s_cnt, s_p0;

  const int row = blockIdx.x;
  const int tid = threadIdx.x;
  const int lane = tid & 63;
  const int wid = tid >> 6;
  const float rp = rps[row];
  const float irp = 1.0f / rp;
  const float itemp = 1.0f / temps[row];
  const float topp = topps[row];
  const int k = topks[row];
  const size_t base = (size_t)row * V;
  const float4* __restrict__ lg4 = reinterpret_cast<const float4*>(logits + base);
  vfloat4* __restrict__ pr4 = reinterpret_cast<vfloat4*>(probs + base);

  for (int i = tid; i < VW; i += 1024) s_seen[i] = 0u;
  for (int i = tid; i < 4096; i += 1024) s_hist[i] = 0;
  __syncthreads();
  for (int i = tid; i < W; i += 1024) {
    int tok = toks[row * W + i];
    if (tok >= 0 && tok < V) atomicOr(&s_seen[tok >> 5], 1u << (tok & 31));
  }
  __syncthreads();

  float lmax = -INFINITY;
  for (int qb = 0; qb < V4; qb += 1024) {
    const int q = qb + tid;
    unsigned int kmax = 0u;
    if (q < V4) {
      float4 x4 = lg4[q];
      float xs[4] = {x4.x, x4.y, x4.z, x4.w};
      const int j0 = q * 4;
      const int sh = j0 & 31;
      unsigned long long ww = (unsigned long long)s_seen[j0 >> 5] |
                              ((unsigned long long)s_seen[(j0 + 3) >> 5] << 32);
#pragma unroll
      for (int e = 0; e < 4; ++e) {
        float x = xform(xs[e], (ww >> (sh + e)) & 1ull, rp, irp, itemp);
        lmax = fmaxf(lmax, x);
        unsigned int ky = fkey(x);
        kmax = kmax > ky ? kmax : ky;
      }
    }
    unsigned int o;
    o = __shfl_xor(kmax, 1); kmax = kmax > o ? kmax : o;
    o = __shfl_xor(kmax, 2); kmax = kmax > o ? kmax : o;
    if (((lane & 3) == 0) && (q < V4)) s_cmax16[q >> 2] = (unsigned short)(kmax >> 16);
  }
#pragma unroll
  for (int d = 32; d > 0; d >>= 1) lmax = fmaxf(lmax, __shfl_xor(lmax, d));
  if (lane == 0) s_wredf[wid] = lmax;
  __syncthreads();
  for (int i = tid; i < NCHUNK; i += 1024)
    atomicAdd(&s_hist[s_cmax16[i] >> 4], 1);
  __syncthreads();
  if (wid == 1 && lane == 0) {
    float mm = s_wredf[0];
    for (int i = 1; i < 16; ++i) mm = fmaxf(mm, s_wredf[i]);
    s_m = mm;
  }
  if (wid == 0) {
    int sm = 0;
    const int bb = lane * 64;
    for (int i = 0; i < 64; ++i) sm += s_hist[bb + i];
    int sfx = sm;
#pragma unroll
    for (int d = 1; d < 64; d <<= 1) {
      int t = __shfl_down(sfx, d);
      if (lane + d < 64) sfx += t;
    }
    unsigned long long mk = __ballot(sfx >= k);
    const int cstar = 63 - __builtin_clzll(mk);
    const int above = __shfl(sfx, cstar) - __shfl(sm, cstar);
    int h = s_hist[cstar * 64 + lane];
    int sfx2 = h;
#pragma unroll
    for (int d = 1; d < 64; d <<= 1) {
      int t = __shfl_down(sfx2, d);
      if (lane + d < 64) sfx2 += t;
    }
    unsigned long long mk2 = __ballot(above + sfx2 >= k);
    const int boff = 63 - __builtin_clzll(mk2);
    if (lane == 0) { s_b0 = cstar * 64 + boff; s_cnt = 0; }
  }
  __syncthreads();
  const int b0 = s_b0;
  const unsigned int fk0 = ((unsigned int)b0) << 20;
  const int c16 = b0 << 4;
  for (int qb = 0; qb < V4; qb += 1024) {
    const int q = qb + tid;
    const bool act = (q < V4) && ((int)s_cmax16[q >> 2] >= c16);
    float xs[4];
    bool pr[4] = {false, false, false, false};
    const int j0 = q * 4;
    if (act) {
      float4 x4 = lg4[q];
      float raw[4] = {x4.x, x4.y, x4.z, x4.w};
      const int sh = j0 & 31;
      unsigned long long ww = (unsigned long long)s_seen[j0 >> 5] |
                              ((unsigned long long)s_seen[(j0 + 3) >> 5] << 32);
#pragma unroll
      for (int e = 0; e < 4; ++e) {
        xs[e] = xform(raw[e], (ww >> (sh + e)) & 1ull, rp, irp, itemp);
        pr[e] = (fkey(xs[e]) >= fk0);
      }
    }
#pragma unroll
    for (int e = 0; e < 4; ++e) {
      unsigned long long mask = __ballot(pr[e]);
      if (!mask) continue;
      int basep = 0;
      if (lane == 0) basep = atomicAdd(&s_cnt, __popcll(mask));
      basep = __shfl(basep, 0);
      if (pr[e]) {
        int pos = basep + __popcll(mask & ((1ull << lane) - 1ull));
        if (pos < CAPM) { s_sval[pos] = xs[e]; s_sidx[pos] = j0 + e; }
      }
    }
  }
  __syncthreads();
  int G = s_cnt;
  if (G > CAPM) G = CAPM;
  int np2 = 2;
  while (np2 < G) np2 <<= 1;
  for (int i = G + tid; i < np2; i += 1024) {
    s_sval[i] = INFINITY;
    s_sidx[i] = 0x7FFFFFFF;
  }
  __syncthreads();
  for (int size = 2; size <= np2; size <<= 1) {
    for (int stride = size >> 1; stride > 0; stride >>= 1) {
      for (int t2 = tid; t2 < (np2 >> 1); t2 += 1024) {
        int pos = 2 * t2 - (t2 & (stride - 1));
        int qq = pos + stride;
        bool up = ((pos & size) == 0);
        float v1 = s_sval[pos], v2 = s_sval[qq];
        int i1 = s_sidx[pos], i2 = s_sidx[qq];
        bool gt = (v1 > v2) || (v1 == v2 && i1 > i2);
        if (gt == up) {
          s_sval[pos] = v2; s_sval[qq] = v1;
          s_sidx[pos] = i2; s_sidx[qq] = i1;
        }
      }
      __syncthreads();
    }
  }
  const int kk = k > G ? G : k;
  const float kth = s_sval[G - kk];
  const float m = s_m;
  for (int i = tid; i < G; i += 1024) {
    if (s_sval[i] >= kth && (i == 0 || s_sval[i - 1] < kth)) s_p0 = i;
  }
  __syncthreads();
  const int p0 = s_p0;
  float part = 0.0f;
  for (int i = p0 + tid; i < G; i += 1024) {
    float e = expf(s_sval[i] - m);
    s_e[i] = e;
    part += e;
  }
#pragma unroll
  for (int d = 32; d > 0; d >>= 1) part += __shfl_xor(part, d);
  if (lane == 0) s_wredf[wid] = part;
  __syncthreads();
  if (tid == 0) {
    float s = 0.0f;
    for (int i = 0; i < 16; ++i) s += s_wredf[i];
    s_denom = s;
  }
  __syncthreads();
  const float denom = s_denom;
  if (tid == 0) {
    const float cut = 1.0f - topp;
    float cs = 0.0f;
    for (int i = p0; i < G; ++i) {
      cs += s_e[i] / denom;
      s_keep[i] = (cs <= cut) ? 0 : 1;
    }
    s_keep[G - 1] = 1;
  }
  __syncthreads();
  part = 0.0f;
  for (int i = p0 + tid; i < G; i += 1024)
    if (s_keep[i]) part += s_e[i];
#pragma unroll
  for (int d = 32; d > 0; d >>= 1) part += __shfl_xor(part, d);
  if (lane == 0) s_wredf[wid] = part;
  __syncthreads();
  if (tid == 0) {
    float s = 0.0f;
    for (int i = 0; i < 16; ++i) s += s_wredf[i];
    s_denom2 = s;
  }
  __syncthreads();
  const float denom2 = s_denom2;
  for (int i = p0 + tid; i < G; i += 1024)
    s_e[i] = s_keep[i] ? (s_e[i] / denom2) : 0.0f;
  __syncthreads();
  float bs = -INFINITY;
  int bi = 0x7FFFFFFF;
  for (int i = p0 + tid; i < G; i += 1024) {
    if (!s_keep[i]) continue;
    int j = s_sidx[i];
    unsigned int t = (unsigned int)(row * V) + (unsigned int)j;
    unsigned int bb = tf_bits(t);
    float u = __uint_as_float((bb >> 9) | 0x3f800000u) - 1.0f;
    if (u < TINYF) u = TINYF;
    float g = -logf(-logf(u));
    float sc = s_sval[i] + g;
    if (sc > bs || (sc == bs && j < bi)) { bs = sc; bi = j; }
  }
  const unsigned int kkey = fkey(kth);
  const int k16 = (int)(kkey >> 16);
  for (int q = tid; q < V4; q += 1024) {
    vfloat4 o = (vfloat4){0.0f, 0.0f, 0.0f, 0.0f};
    if ((int)s_cmax16[q >> 2] >= k16) {
      float4 x4 = lg4[q];
      float raw[4] = {x4.x, x4.y, x4.z, x4.w};
      float os[4];
      const int j0 = q * 4;
      const int sh = j0 & 31;
      unsigned long long ww = (unsigned long long)s_seen[j0 >> 5] |
                              ((unsigned long long)s_seen[(j0 + 3) >> 5] << 32);
#pragma unroll
      for (int e = 0; e < 4; ++e) {
        float x = xform(raw[e], (ww >> (sh + e)) & 1ull, rp, irp, itemp);
        float pr = 0.0f;
        if (x >= kth) {
          int j = j0 + e;
          int lo = p0, hi = G;
          while (lo < hi) {
            int mid = (lo + hi) >> 1;
            float v = s_sval[mid];
            int id = s_sidx[mid];
            if (v < x || (v == x && id < j)) lo = mid + 1; else hi = mid;
          }
          pr = s_e[lo];
        }
        os[e] = pr;
      }
      o.x = os[0]; o.y = os[1]; o.z = os[2]; o.w = os[3];
    }
    pr4[q] = o;
  }
#pragma unroll
  for (int d = 32; d > 0; d >>= 1) {
    float ov = __shfl_down(bs, d);
    int oi = __shfl_down(bi, d);
    if (ov > bs || (ov == bs && oi < bi)) { bs = ov; bi = oi; }
  }
  if (lane == 0) { s_wredf[wid] = bs; s_wredi[wid] = bi; }
  __syncthreads();
  if (tid == 0) {
    float bb = s_wredf[0];
    int bj = s_wredi[0];
    for (int i = 1; i < 16; ++i) {
      if (s_wredf[i] > bb || (s_wredf[i] == bb && s_wredi[i] < bj)) {
        bb = s_wredf[i];
        bj = s_wredi[i];
      }
    }
    out_ids[row] = (float)bj;
  }
}

extern "C" void kernel_launch(void* const* d_in, const int* in_sizes, int n_in,
                              void* d_out, int out_size, void* d_ws, size_t ws_size,
                              hipStream_t stream) {
  (void)in_sizes; (void)out_size;
  if (n_in < 6) return;
  const float* logits = (const float*)d_in[0];
  const int* toks = (const int*)d_in[1];
  const float* temps = (const float*)d_in[2];
  const float* topps = (const float*)d_in[3];
  const int* topks = (const int*)d_in[4];
  const float* rps = (const float*)d_in[5];
  float* out = (float*)d_out;            // [0,256): ids as float; [256,...): probs
  float* probs = out + NROWS;

  if (ws_size >= WS_NEED && d_ws != nullptr) {
    char* w = (char*)d_ws;
    unsigned short* ws_cmax = (unsigned short*)(w + WS_CMAX);
    float* ws_bmax = (float*)(w + WS_BMAX);
    int* ws_b0 = (int*)(w + WS_B0);
    int* ws_cnt = (int*)(w + WS_CNT);
    unsigned long long* ws_keys = (unsigned long long*)(w + WS_KEYS);
    kF_zero<<<dim3(2048), dim3(256), 0, stream>>>(probs);
    kA_chunkmax<<<dim3(NROWS * NSLICE), dim3(256), 0, stream>>>(
        logits, toks, temps, rps, ws_cmax, ws_bmax);
    kS_b0<<<dim3(NROWS), dim3(1024), 0, stream>>>(ws_cmax, topks, ws_b0, ws_cnt);
    kB1_gather<<<dim3(NROWS * NSLICE), dim3(256), 0, stream>>>(
        logits, toks, temps, rps, ws_cmax, ws_b0, ws_cnt, ws_keys);
    kB2_finish<<<dim3(NROWS), dim3(1024), 0, stream>>>(
        topps, topks, ws_bmax, ws_cnt, ws_keys, out, probs);
  } else {
    sampler_mono<<<dim3(NROWS), dim3(1024), 0, stream>>>(
        logits, toks, temps, topps, topks, rps, out, probs);
  }
}

// Round 17
// 101.999 us; speedup vs baseline: 2.0156x; 1.2478x over previous
//
#include <hip/hip_runtime.h>

#define V 128000
#define V4 (V / 4)
#define NROWS 256
#define V4ALL (NROWS * V4)
#define NCHUNK (V / 16)      // 8000 chunk-max entries
#define NSLICE 8
#define SL4 (V4 / NSLICE)    // 4000 float4 per slice
#define SLC (NCHUNK / NSLICE)// 1000 chunks per slice
#define W 200
#define VW (V / 32)
#define CAP 4096             // total candidate capacity (= 8*SEG + OVF)
#define SEG 448              // per-slice private segment
#define OVF 512              // overflow slots
#define OVF_BASE (NSLICE * SEG)   // 3584
#define CAPS 2048            // survivor capacity
#define CAPM 8192            // mono-kernel capacity
#define TINYF 1.17549435e-38f
#define HIDX(b) ((b) + ((b) >> 5))
#define HSZ 4224

// ---- d_ws layout ----
#define WS_CMAX   0u          // u16[256][8000] = 4,096,000
#define WS_BMAX   4104192u    // float[256][8]
#define WS_B0     4112384u    // int[256]
#define WS_CNT8   4113408u    // int[256][8]
#define WS_OVF    4121600u    // int[256]
#define WS_KEYS   8388608u    // u64[256][4096] = 8 MiB
#define WS_NEED   16777216u

typedef float vfloat4 __attribute__((ext_vector_type(4)));

__device__ __forceinline__ void bar_lds() {
  asm volatile("s_waitcnt lgkmcnt(0)" ::: "memory");
  __builtin_amdgcn_s_barrier();
}

__device__ __forceinline__ unsigned int fkey(float x) {
  unsigned int u = __float_as_uint(x);
  return (u & 0x80000000u) ? ~u : (u | 0x80000000u);
}
__device__ __forceinline__ float ikey(unsigned int k) {
  unsigned int u = (k & 0x80000000u) ? (k & 0x7FFFFFFFu) : ~k;
  return __uint_as_float(u);
}

// ---- jax threefry2x32, partitionable: counter=(0,t), key=(0,42), fold=xor ----
__device__ __forceinline__ unsigned int tf_bits(unsigned int t) {
  const unsigned int k0 = 0u, k1 = 42u;
  const unsigned int ks2 = k0 ^ k1 ^ 0x1BD11BDAu;
  unsigned int x0 = 0u + k0, x1 = t + k1;
  const unsigned int ksArr[3] = {k0, k1, ks2};
  const int RA[4] = {13, 15, 26, 6};
  const int RB[4] = {17, 29, 16, 24};
#pragma unroll
  for (int i = 0; i < 5; ++i) {
#pragma unroll
    for (int j = 0; j < 4; ++j) {
      int r = (i & 1) ? RB[j] : RA[j];
      x0 += x1;
      x1 = (x1 << r) | (x1 >> (32 - r));
      x1 ^= x0;
    }
    x0 += ksArr[(i + 1) % 3];
    x1 += ksArr[(i + 2) % 3] + (unsigned int)(i + 1);
  }
  return x0 ^ x1;
}

__device__ __forceinline__ float xform(float x, bool seen, float rp, float irp,
                                        float itemp) {
  if (seen) x = (x > 0.0f) ? x * irp : x * rp;
  return x * itemp;
}

// Wave-parallel suffix select over a padded 4096-bucket histogram (one wave).
__device__ __forceinline__ void wave_suffix_select_p(const int* hist, int need,
                                                     int lane, int* out_b,
                                                     int* out_rem) {
  int sm = 0;
  const int bb = lane * 64;
  for (int i = 0; i < 64; ++i) sm += hist[HIDX(bb + i)];
  int sfx = sm;
#pragma unroll
  for (int d = 1; d < 64; d <<= 1) {
    int t = __shfl_down(sfx, d);
    if (lane + d < 64) sfx += t;
  }
  unsigned long long mk = __ballot(sfx >= need);
  const int cstar = 63 - __builtin_clzll(mk);
  const int aboveC = __shfl(sfx, cstar) - __shfl(sm, cstar);
  int h = hist[HIDX(cstar * 64 + lane)];
  int sfx2 = h;
#pragma unroll
  for (int d = 1; d < 64; d <<= 1) {
    int t = __shfl_down(sfx2, d);
    if (lane + d < 64) sfx2 += t;
  }
  unsigned long long mk2 = __ballot(aboveC + sfx2 >= need);
  const int boff = 63 - __builtin_clzll(mk2);
  const int aboveB = aboveC + __shfl(sfx2, boff) - __shfl(h, boff);
  if (lane == 0) {
    *out_b = cstar * 64 + boff;
    *out_rem = need - aboveB;
  }
}

// ====== Kernel A: transform + chunk-max + slice-max (pure read) ======
__global__ __launch_bounds__(256) void kA_chunkmax(
    const float* __restrict__ logits, const int* __restrict__ toks,
    const float* __restrict__ temps, const float* __restrict__ rps,
    unsigned short* __restrict__ ws_cmax, float* __restrict__ ws_bmax) {
  __shared__ unsigned int s_seen[VW];
  __shared__ float s_red[4];
  const int row = blockIdx.x >> 3;
  const int slice = blockIdx.x & 7;
  const int tid = threadIdx.x;
  const int lane = tid & 63;
  const int wid = tid >> 6;
  const float rp = rps[row];
  const float irp = 1.0f / rp;
  const float itemp = 1.0f / temps[row];
  const size_t base = (size_t)row * V;
  const float4* __restrict__ lg4 = reinterpret_cast<const float4*>(logits + base);

  for (int i = tid; i < VW; i += 256) s_seen[i] = 0u;
  __syncthreads();
  for (int i = tid; i < W; i += 256) {
    int tok = toks[row * W + i];
    if (tok >= 0 && tok < V) atomicOr(&s_seen[tok >> 5], 1u << (tok & 31));
  }
  __syncthreads();

  float lmax = -INFINITY;
  const int q0 = slice * SL4;
  for (int qi = tid; qi < SL4; qi += 256) {
    const int q = q0 + qi;
    float4 x4 = lg4[q];
    float xs[4] = {x4.x, x4.y, x4.z, x4.w};
    const int j0 = q * 4;
    const int sh = j0 & 31;
    unsigned long long ww = (unsigned long long)s_seen[j0 >> 5] |
                            ((unsigned long long)s_seen[(j0 + 3) >> 5] << 32);
    unsigned int kmax = 0u;
#pragma unroll
    for (int e = 0; e < 4; ++e) {
      float x = xform(xs[e], (ww >> (sh + e)) & 1ull, rp, irp, itemp);
      lmax = fmaxf(lmax, x);
      unsigned int ky = fkey(x);
      kmax = kmax > ky ? kmax : ky;
    }
    unsigned int o;
    o = __shfl_xor(kmax, 1); kmax = kmax > o ? kmax : o;
    o = __shfl_xor(kmax, 2); kmax = kmax > o ? kmax : o;
    if ((lane & 3) == 0) ws_cmax[row * NCHUNK + (q >> 2)] = (unsigned short)(kmax >> 16);
  }
#pragma unroll
  for (int d = 32; d > 0; d >>= 1) lmax = fmaxf(lmax, __shfl_xor(lmax, d));
  if (lane == 0) s_red[wid] = lmax;
  __syncthreads();
  if (tid == 0) {
    float mm = fmaxf(fmaxf(s_red[0], s_red[1]), fmaxf(s_red[2], s_red[3]));
    ws_bmax[row * NSLICE + slice] = mm;
  }
}

// ====== Kernel S: per-row b0 select from chunk-max histogram (4x replicated) ======
__global__ __launch_bounds__(1024) void kS_b0(
    const unsigned short* __restrict__ ws_cmax, const int* __restrict__ topks,
    int* __restrict__ ws_b0, int* __restrict__ ws_ovf) {
  __shared__ int s_h[4 * HSZ];   // 67.6 KB
  __shared__ int s_b, s_rem;
  const int row = blockIdx.x;
  const int tid = threadIdx.x;
  const int lane = tid & 63;
  const int wid = tid >> 6;
  for (int i = tid; i < 4 * HSZ; i += 1024) s_h[i] = 0;
  __syncthreads();
  const unsigned short* cm = ws_cmax + row * NCHUNK;
  const int rep = (tid & 3) * HSZ;
  for (int i = tid; i < NCHUNK; i += 1024)
    atomicAdd(&s_h[rep + HIDX(cm[i] >> 4)], 1);
  __syncthreads();
  for (int i = tid; i < HSZ; i += 1024)
    s_h[i] += s_h[i + HSZ] + s_h[i + 2 * HSZ] + s_h[i + 3 * HSZ];
  __syncthreads();
  if (wid == 0) wave_suffix_select_p(s_h, topks[row], lane, &s_b, &s_rem);
  __syncthreads();
  if (tid == 0) {
    ws_b0[row] = s_b;
    ws_ovf[row] = 0;
  }
}

// ====== Kernel B1: single-pass gather to PRIVATE per-slice segment +
//        zero-fill of this slice's probs (stores drain under 8-block/CU TLP) ======
__global__ __launch_bounds__(256) void kB1_gather(
    const float* __restrict__ logits, const int* __restrict__ toks,
    const float* __restrict__ temps, const float* __restrict__ rps,
    const unsigned short* __restrict__ ws_cmax, const int* __restrict__ ws_b0,
    int* __restrict__ ws_cnt8, int* __restrict__ ws_ovf,
    unsigned long long* __restrict__ ws_keys, float* __restrict__ probs) {
  __shared__ unsigned int s_seen[VW];     // 16 KB
  __shared__ unsigned short s_cm[SLC];    // 2 KB
  __shared__ int s_cnt;
  const int row = blockIdx.x >> 3;
  const int slice = blockIdx.x & 7;
  const int tid = threadIdx.x;
  const int lane = tid & 63;
  const float rp = rps[row];
  const float irp = 1.0f / rp;
  const float itemp = 1.0f / temps[row];
  const size_t base = (size_t)row * V;
  const float4* __restrict__ lg4 = reinterpret_cast<const float4*>(logits + base);
  vfloat4* __restrict__ pr4 = reinterpret_cast<vfloat4*>(probs + base);

  if (tid == 0) s_cnt = 0;
  for (int i = tid; i < VW; i += 256) s_seen[i] = 0u;
  for (int i = tid; i < SLC; i += 256)
    s_cm[i] = ws_cmax[row * NCHUNK + slice * SLC + i];
  __syncthreads();
  for (int i = tid; i < W; i += 256) {
    int tok = toks[row * W + i];
    if (tok >= 0 && tok < V) atomicOr(&s_seen[tok >> 5], 1u << (tok & 31));
  }
  __syncthreads();

  const int b0 = ws_b0[row];
  const unsigned int fk0 = ((unsigned int)b0) << 20;
  const int c16 = b0 << 4;
  unsigned long long* __restrict__ krow = ws_keys + (size_t)row * CAP;
  unsigned long long* __restrict__ kseg = krow + slice * SEG;
  const int q0 = slice * SL4;

  // uniform-trip loop: wave-wide ballots/shuffles stay wave-uniform
  for (int qb = 0; qb < SL4; qb += 256) {
    const int qi = qb + tid;
    const bool inb = (qi < SL4);
    const bool act = inb && ((int)s_cm[qi >> 2] >= c16);
    const int q = q0 + qi;
    const int j0 = q * 4;
    unsigned int ks[4];
    bool pr[4] = {false, false, false, false};
    if (act) {
      float4 x4 = lg4[q];
      float raw[4] = {x4.x, x4.y, x4.z, x4.w};
      const int sh = j0 & 31;
      unsigned long long ww = (unsigned long long)s_seen[j0 >> 5] |
                              ((unsigned long long)s_seen[(j0 + 3) >> 5] << 32);
#pragma unroll
      for (int e = 0; e < 4; ++e) {
        float x = xform(raw[e], (ww >> (sh + e)) & 1ull, rp, irp, itemp);
        ks[e] = fkey(x);
        pr[e] = (ks[e] >= fk0);
      }
    }
#pragma unroll
    for (int e = 0; e < 4; ++e) {
      unsigned long long mask = __ballot(pr[e]);
      if (!mask) continue;
      int basep = 0;
      if (lane == 0) basep = atomicAdd(&s_cnt, __popcll(mask));
      basep = __shfl(basep, 0);
      if (pr[e]) {
        int pos = basep + __popcll(mask & ((1ull << lane) - 1ull));
        unsigned long long key =
            ((unsigned long long)ks[e] << 32) | (unsigned int)(j0 + e);
        if (pos < SEG) {
          kseg[pos] = key;
        } else {                      // rare overflow path
          int op = atomicAdd(&ws_ovf[row], 1);
          if (op < OVF) krow[OVF_BASE + op] = key;
        }
      }
    }
  }
  __syncthreads();
  if (tid == 0) ws_cnt8[row * NSLICE + slice] = s_cnt < SEG ? s_cnt : SEG;

  // ---- zero-fill this slice of probs (pure stores at end; TLP hides drain) ----
  const vfloat4 z4 = (vfloat4){0.0f, 0.0f, 0.0f, 0.0f};
  for (int qi = tid; qi < SL4; qi += 256) pr4[q0 + qi] = z4;
}

// ====== Kernel B2: ingest segments + radix-kth + counting sort + top-p + sample ======
__global__ __launch_bounds__(1024) void kB2_finish(
    const float* __restrict__ topps, const int* __restrict__ topks,
    const float* __restrict__ ws_bmax, const int* __restrict__ ws_cnt8,
    const int* __restrict__ ws_ovf, const unsigned long long* __restrict__ ws_keys,
    float* __restrict__ out_ids, float* __restrict__ probs) {
  __shared__ unsigned long long s_key[CAP];             // 32 KB: keys; later sorted+overlays
  __shared__ __align__(16) int s_h[4 * HSZ];            // 67.6 KB: replicated hists -> keep
  __shared__ __align__(16) unsigned char s_bufB[16384]; // 16 KB: survivors (unsorted)
  __shared__ float s_wredf[16];
  __shared__ int s_wredi[16];
  __shared__ float s_mv, s_dn1, s_dn2;
  __shared__ int s_scnt, s_selb, s_selrem, s_p0v, s_maxpop;
  __shared__ int s_base[9], s_ovfn;

  unsigned long long* s_key2 = (unsigned long long*)s_bufB;
  unsigned long long* s_skey = s_key;
  float* s_e2 = (float*)(s_key + CAPS);
  float* s_q2 = (float*)(s_key + CAPS + CAPS / 2);
  unsigned char* s_keep = (unsigned char*)s_h;          // overlay (hists dead post-sort)

  const int row = blockIdx.x;
  const int tid = threadIdx.x;
  const int lane = tid & 63;
  const int wid = tid >> 6;
  const float topp = topps[row];
  const int k = topks[row];
  float* __restrict__ prow = probs + (size_t)row * V;
  const unsigned long long* __restrict__ krow = ws_keys + (size_t)row * CAP;

  if (tid == 0) {
    int acc = 0;
    for (int s = 0; s < NSLICE; ++s) {
      s_base[s] = acc;
      acc += ws_cnt8[row * NSLICE + s];
    }
    s_base[8] = acc;
    int ov = ws_ovf[row];
    s_ovfn = ov > OVF ? OVF : ov;
  }
  if (wid == 1 && lane == 0) {
    float mm = ws_bmax[row * NSLICE];
    for (int i = 1; i < NSLICE; ++i) mm = fmaxf(mm, ws_bmax[row * NSLICE + i]);
    s_mv = mm;
  }
  for (int i = tid; i < 4 * HSZ; i += 1024) s_h[i] = 0;
  __syncthreads();

  // ---- ingest 8 segments + overflow into contiguous s_key[0, G) ----
#pragma unroll
  for (int s = 0; s < NSLICE; ++s) {
    const int b = s_base[s];
    const int c = s_base[s + 1] - b;     // valid: s_base[8] caps last
    for (int i = tid; i < c; i += 1024) s_key[b + i] = krow[s * SEG + i];
  }
  {
    const int sum8 = s_base[8];
    for (int i = tid; i < s_ovfn; i += 1024)
      s_key[sum8 + i] = krow[OVF_BASE + i];
  }
  int G = s_base[8] + s_ovfn;
  if (G > CAP) G = CAP;
  const int kk = k > G ? G : k;
  bar_lds();

  // ---- 1-pass radix (replicated): bucket (fkey>>20) of the kk-th largest ----
  const int rep = (tid & 3) * HSZ;
  for (int i = tid; i < G; i += 1024)
    atomicAdd(&s_h[rep + HIDX((unsigned int)(s_key[i] >> 52))], 1);
  bar_lds();
  for (int i = tid; i < HSZ; i += 1024)
    s_h[i] += s_h[i + HSZ] + s_h[i + 2 * HSZ] + s_h[i + 3 * HSZ];
  bar_lds();
  if (wid == 0) {
    wave_suffix_select_p(s_h, kk, lane, &s_selb, &s_selrem);
    if (lane == 0) s_scnt = 0;
  }
  bar_lds();
  const unsigned int b1 = (unsigned int)s_selb;

  // ---- compact survivor-superset (top12 >= b1) into s_key2 ----
  for (int ib = 0; ib < G; ib += 1024) {
    const int i = ib + tid;
    const bool p = (i < G) && ((unsigned int)(s_key[i] >> 52) >= b1);
    unsigned long long mask = __ballot(p);
    if (!mask) continue;
    int basep = 0;
    if (lane == 0) basep = atomicAdd(&s_scnt, __popcll(mask));
    basep = __shfl(basep, 0);
    if (p) {
      int pos = basep + __popcll(mask & ((1ull << lane) - 1ull));
      if (pos < CAPS) s_key2[pos] = s_key[i];
    }
  }
  bar_lds();
  int S = s_scnt;
  if (S > CAPS) S = CAPS;
  const float m = s_mv;

  // ---- counting sort by value bins (replicated counts), bitonic fallback ----
  const unsigned int cbase = b1 << 20;
  const unsigned int span = fkey(m) - cbase;
  int shiftb;
  {
    int bits = 32 - __clz((int)(span | 1u));
    shiftb = bits > 12 ? bits - 12 : 0;
  }
  for (int i = tid; i < 4 * HSZ; i += 1024) s_h[i] = 0;
  bar_lds();
  for (int i = tid; i < S; i += 1024) {
    unsigned int hi = (unsigned int)(s_key2[i] >> 32);
    int b = (int)((hi - cbase) >> shiftb);
    if (b > 4095) b = 4095;
    atomicAdd(&s_h[rep + HIDX(b)], 1);
  }
  bar_lds();
  for (int i = tid; i < HSZ; i += 1024)
    s_h[i] += s_h[i + HSZ] + s_h[i + 2 * HSZ] + s_h[i + 3 * HSZ];
  bar_lds();
  if (wid == 0) {
    int T = 0, mx = 0;
    const int bb = lane * 64;
    for (int i = 0; i < 64; ++i) {
      int c = s_h[HIDX(bb + i)];
      T += c;
      mx = c > mx ? c : mx;
    }
    int ex = T;
#pragma unroll
    for (int d = 1; d < 64; d <<= 1) {
      int t = __shfl_up(ex, d);
      if (lane >= d) ex += t;
    }
    ex -= T;
    int run = ex;
    for (int i = 0; i < 64; ++i) {
      int idx = HIDX(bb + i);
      int c = s_h[idx];
      s_h[idx] = run;
      run += c;
    }
#pragma unroll
    for (int d = 32; d > 0; d >>= 1) {
      int o = __shfl_xor(mx, d);
      mx = o > mx ? o : mx;
    }
    if (lane == 0) s_maxpop = mx;
  }
  bar_lds();

  if (s_maxpop <= 16) {
    for (int i = tid; i < S; i += 1024) {
      unsigned long long key = s_key2[i];
      unsigned int hi = (unsigned int)(key >> 32);
      int b = (int)((hi - cbase) >> shiftb);
      if (b > 4095) b = 4095;
      int pos = atomicAdd(&s_h[HIDX(b)], 1);
      s_skey[pos] = key;
    }
    bar_lds();
    for (int b = tid; b < 4096; b += 1024) {
      int endb = s_h[HIDX(b)];
      int st = (b == 0) ? 0 : s_h[HIDX(b - 1)];
      for (int i = st + 1; i < endb; ++i) {
        unsigned long long key = s_skey[i];
        int j = i - 1;
        while (j >= st && s_skey[j] > key) {
          s_skey[j + 1] = s_skey[j];
          --j;
        }
        s_skey[j + 1] = key;
      }
    }
    bar_lds();
  } else {
    int np2 = 2;
    while (np2 < S) np2 <<= 1;
    for (int i = S + tid; i < np2; i += 1024) s_key2[i] = ~0ull;
    bar_lds();
    for (int size = 2; size <= np2; size <<= 1) {
      for (int stride = size >> 1; stride > 0; stride >>= 1) {
        for (int t2 = tid; t2 < (np2 >> 1); t2 += 1024) {
          int pos = 2 * t2 - (t2 & (stride - 1));
          int qq = pos + stride;
          bool up = ((pos & size) == 0);
          unsigned long long a = s_key2[pos], b = s_key2[qq];
          if ((a > b) == up) { s_key2[pos] = b; s_key2[qq] = a; }
        }
        bar_lds();
      }
    }
    for (int i = tid; i < S; i += 1024) s_skey[i] = s_key2[i];
    bar_lds();
  }

  // ---- exact kth + survivor range [p0, S) ----
  const unsigned int kthkey32 = (unsigned int)(s_skey[S - kk] >> 32);
  for (int i = tid; i < S; i += 1024) {
    unsigned int hi = (unsigned int)(s_skey[i] >> 32);
    if (hi >= kthkey32 && (i == 0 || (unsigned int)(s_skey[i - 1] >> 32) < kthkey32))
      s_p0v = i;
  }
  bar_lds();
  const int p0 = s_p0v;
  const int L = S - p0;

  // ---- softmax denom over survivors ----
  float part = 0.0f;
  for (int i = tid; i < L; i += 1024) {
    float x = ikey((unsigned int)(s_skey[p0 + i] >> 32));
    float e = expf(x - m);
    s_e2[i] = e;
    part += e;
  }
#pragma unroll
  for (int d = 32; d > 0; d >>= 1) part += __shfl_xor(part, d);
  if (lane == 0) s_wredf[wid] = part;
  bar_lds();
  if (tid == 0) {
    float s = 0.0f;
    for (int i = 0; i < 16; ++i) s += s_wredf[i];
    s_dn1 = s;
  }
  bar_lds();
  const float denom = s_dn1;

  for (int i = tid; i < L; i += 1024) s_q2[i] = s_e2[i] / denom;
  bar_lds();

  // ---- serial fp32 cumsum (pure add chain) + top-p mask, last kept ----
  if (tid == 0) {
    const float cut = 1.0f - topp;
    float cs = 0.0f;
    int i = 0;
    for (; i + 16 <= L; i += 16) {
      vfloat4 a = *(const vfloat4*)&s_q2[i];
      vfloat4 b = *(const vfloat4*)&s_q2[i + 4];
      vfloat4 c = *(const vfloat4*)&s_q2[i + 8];
      vfloat4 d = *(const vfloat4*)&s_q2[i + 12];
      unsigned int w0, w1, w2, w3;
      cs += a.x; w0  = (cs <= cut) ? 0u : 1u;
      cs += a.y; w0 |= ((cs <= cut) ? 0u : 1u) << 8;
      cs += a.z; w0 |= ((cs <= cut) ? 0u : 1u) << 16;
      cs += a.w; w0 |= ((cs <= cut) ? 0u : 1u) << 24;
      cs += b.x; w1  = (cs <= cut) ? 0u : 1u;
      cs += b.y; w1 |= ((cs <= cut) ? 0u : 1u) << 8;
      cs += b.z; w1 |= ((cs <= cut) ? 0u : 1u) << 16;
      cs += b.w; w1 |= ((cs <= cut) ? 0u : 1u) << 24;
      cs += c.x; w2  = (cs <= cut) ? 0u : 1u;
      cs += c.y; w2 |= ((cs <= cut) ? 0u : 1u) << 8;
      cs += c.z; w2 |= ((cs <= cut) ? 0u : 1u) << 16;
      cs += c.w; w2 |= ((cs <= cut) ? 0u : 1u) << 24;
      cs += d.x; w3  = (cs <= cut) ? 0u : 1u;
      cs += d.y; w3 |= ((cs <= cut) ? 0u : 1u) << 8;
      cs += d.z; w3 |= ((cs <= cut) ? 0u : 1u) << 16;
      cs += d.w; w3 |= ((cs <= cut) ? 0u : 1u) << 24;
      *(unsigned int*)&s_keep[i] = w0;
      *(unsigned int*)&s_keep[i + 4] = w1;
      *(unsigned int*)&s_keep[i + 8] = w2;
      *(unsigned int*)&s_keep[i + 12] = w3;
    }
    for (; i < L; ++i) {
      cs += s_q2[i];
      s_keep[i] = (cs <= cut) ? 0 : 1;
    }
    s_keep[L - 1] = 1;
  }
  bar_lds();

  // ---- final denom over kept ----
  part = 0.0f;
  for (int i = tid; i < L; i += 1024)
    if (s_keep[i]) part += s_e2[i];
#pragma unroll
  for (int d = 32; d > 0; d >>= 1) part += __shfl_xor(part, d);
  if (lane == 0) s_wredf[wid] = part;
  bar_lds();
  if (tid == 0) {
    float s = 0.0f;
    for (int i = 0; i < 16; ++i) s += s_wredf[i];
    s_dn2 = s;
  }
  bar_lds();
  const float denom2 = s_dn2;

  for (int i = tid; i < L; i += 1024)
    s_e2[i] = s_keep[i] ? (s_e2[i] / denom2) : 0.0f;
  bar_lds();

  // ---- Gumbel argmax over kept survivors ----
  float bs = -INFINITY;
  int bi = 0x7FFFFFFF;
  for (int i = tid; i < L; i += 1024) {
    if (!s_keep[i]) continue;
    unsigned long long kv = s_skey[p0 + i];
    int j = (int)(kv & 0xFFFFFFFFull);
    float x = ikey((unsigned int)(kv >> 32));
    unsigned int t = (unsigned int)(row * V) + (unsigned int)j;
    unsigned int bb = tf_bits(t);
    float u = __uint_as_float((bb >> 9) | 0x3f800000u) - 1.0f;
    if (u < TINYF) u = TINYF;
    float g = -logf(-logf(u));
    float sc = x + g;
    if (sc > bs || (sc == bs && j < bi)) { bs = sc; bi = j; }
  }

  // ---- scatter nonzero probs (zeros laid down by kB1's fill) ----
  for (int i = tid; i < L; i += 1024) {
    int j = (int)(s_skey[p0 + i] & 0xFFFFFFFFull);
    prow[j] = s_e2[i];
  }

  // ---- argmax reduce -> sampled id ----
#pragma unroll
  for (int d = 32; d > 0; d >>= 1) {
    float ov = __shfl_down(bs, d);
    int oi = __shfl_down(bi, d);
    if (ov > bs || (ov == bs && oi < bi)) { bs = ov; bi = oi; }
  }
  if (lane == 0) { s_wredf[wid] = bs; s_wredi[wid] = bi; }
  bar_lds();
  if (tid == 0) {
    float bb = s_wredf[0];
    int bj = s_wredi[0];
    for (int i = 1; i < 16; ++i) {
      if (s_wredf[i] > bb || (s_wredf[i] == bb && s_wredi[i] < bj)) {
        bb = s_wredf[i];
        bj = s_wredi[i];
      }
    }
    out_ids[row] = (float)bj;
  }
}

// ================== Fallback: monolithic kernel (ws too small) ==================
__global__ __launch_bounds__(1024, 1) void sampler_mono(
    const float* __restrict__ logits, const int* __restrict__ toks,
    const float* __restrict__ temps, const float* __restrict__ topps,
    const int* __restrict__ topks, const float* __restrict__ rps,
    float* __restrict__ out_ids, float* __restrict__ probs) {
  __shared__ unsigned int s_seen[VW];
  __shared__ int s_hist[4096];
  __shared__ unsigned short s_cmax16[NCHUNK];
  __shared__ float s_sval[CAPM];
  __shared__ int s_sidx[CAPM];
  __shared__ float s_e[CAPM];
  __shared__ unsigned char s_keep[CAPM];
  __shared__ float s_wredf[16];
  __shared__ int s_wredi[16];
  __shared__ float s_m, s_denom, s_denom2;
  __shared__ int s_b0, s_cnt, s_p0;

  const int row = blockIdx.x;
  const int tid = threadIdx.x;
  const int lane = tid & 63;
  const int wid = tid >> 6;
  const float rp = rps[row];
  const float irp = 1.0f / rp;
  const float itemp = 1.0f / temps[row];
  const float topp = topps[row];
  const int k = topks[row];
  const size_t base = (size_t)row * V;
  const float4* __restrict__ lg4 = reinterpret_cast<const float4*>(logits + base);
  vfloat4* __restrict__ pr4 = reinterpret_cast<vfloat4*>(probs + base);

  for (int i = tid; i < VW; i += 1024) s_seen[i] = 0u;
  for (int i = tid; i < 4096; i += 1024) s_hist[i] = 0;
  __syncthreads();
  for (int i = tid; i < W; i += 1024) {
    int tok = toks[row * W + i];
    if (tok >= 0 && tok < V) atomicOr(&s_seen[tok >> 5], 1u << (tok & 31));
  }
  __syncthreads();

  float lmax = -INFINITY;
  for (int qb = 0; qb < V4; qb += 1024) {
    const int q = qb + tid;
    unsigned int kmax = 0u;
    if (q < V4) {
      float4 x4 = lg4[q];
      float xs[4] = {x4.x, x4.y, x4.z, x4.w};
      const int j0 = q * 4;
      const int sh = j0 & 31;
      unsigned long long ww = (unsigned long long)s_seen[j0 >> 5] |
                              ((unsigned long long)s_seen[(j0 + 3) >> 5] << 32);
#pragma unroll
      for (int e = 0; e < 4; ++e) {
        float x = xform(xs[e], (ww >> (sh + e)) & 1ull, rp, irp, itemp);
        lmax = fmaxf(lmax, x);
        unsigned int ky = fkey(x);
        kmax = kmax > ky ? kmax : ky;
      }
    }
    unsigned int o;
    o = __shfl_xor(kmax, 1); kmax = kmax > o ? kmax : o;
    o = __shfl_xor(kmax, 2); kmax = kmax > o ? kmax : o;
    if (((lane & 3) == 0) && (q < V4)) s_cmax16[q >> 2] = (unsigned short)(kmax >> 16);
  }
#pragma unroll
  for (int d = 32; d > 0; d >>= 1) lmax = fmaxf(lmax, __shfl_xor(lmax, d));
  if (lane == 0) s_wredf[wid] = lmax;
  __syncthreads();
  for (int i = tid; i < NCHUNK; i += 1024)
    atomicAdd(&s_hist[s_cmax16[i] >> 4], 1);
  __syncthreads();
  if (wid == 1 && lane == 0) {
    float mm = s_wredf[0];
    for (int i = 1; i < 16; ++i) mm = fmaxf(mm, s_wredf[i]);
    s_m = mm;
  }
  if (wid == 0) {
    int sm = 0;
    const int bb = lane * 64;
    for (int i = 0; i < 64; ++i) sm += s_hist[bb + i];
    int sfx = sm;
#pragma unroll
    for (int d = 1; d < 64; d <<= 1) {
      int t = __shfl_down(sfx, d);
      if (lane + d < 64) sfx += t;
    }
    unsigned long long mk = __ballot(sfx >= k);
    const int cstar = 63 - __builtin_clzll(mk);
    const int above = __shfl(sfx, cstar) - __shfl(sm, cstar);
    int h = s_hist[cstar * 64 + lane];
    int sfx2 = h;
#pragma unroll
    for (int d = 1; d < 64; d <<= 1) {
      int t = __shfl_down(sfx2, d);
      if (lane + d < 64) sfx2 += t;
    }
    unsigned long long mk2 = __ballot(above + sfx2 >= k);
    const int boff = 63 - __builtin_clzll(mk2);
    if (lane == 0) { s_b0 = cstar * 64 + boff; s_cnt = 0; }
  }
  __syncthreads();
  const int b0 = s_b0;
  const unsigned int fk0 = ((unsigned int)b0) << 20;
  const int c16 = b0 << 4;
  for (int qb = 0; qb < V4; qb += 1024) {
    const int q = qb + tid;
    const bool act = (q < V4) && ((int)s_cmax16[q >> 2] >= c16);
    float xs[4];
    bool pr[4] = {false, false, false, false};
    const int j0 = q * 4;
    if (act) {
      float4 x4 = lg4[q];
      float raw[4] = {x4.x, x4.y, x4.z, x4.w};
      const int sh = j0 & 31;
      unsigned long long ww = (unsigned long long)s_seen[j0 >> 5] |
                              ((unsigned long long)s_seen[(j0 + 3) >> 5] << 32);
#pragma unroll
      for (int e = 0; e < 4; ++e) {
        xs[e] = xform(raw[e], (ww >> (sh + e)) & 1ull, rp, irp, itemp);
        pr[e] = (fkey(xs[e]) >= fk0);
      }
    }
#pragma unroll
    for (int e = 0; e < 4; ++e) {
      unsigned long long mask = __ballot(pr[e]);
      if (!mask) continue;
      int basep = 0;
      if (lane == 0) basep = atomicAdd(&s_cnt, __popcll(mask));
      basep = __shfl(basep, 0);
      if (pr[e]) {
        int pos = basep + __popcll(mask & ((1ull << lane) - 1ull));
        if (pos < CAPM) { s_sval[pos] = xs[e]; s_sidx[pos] = j0 + e; }
      }
    }
  }
  __syncthreads();
  int G = s_cnt;
  if (G > CAPM) G = CAPM;
  int np2 = 2;
  while (np2 < G) np2 <<= 1;
  for (int i = G + tid; i < np2; i += 1024) {
    s_sval[i] = INFINITY;
    s_sidx[i] = 0x7FFFFFFF;
  }
  __syncthreads();
  for (int size = 2; size <= np2; size <<= 1) {
    for (int stride = size >> 1; stride > 0; stride >>= 1) {
      for (int t2 = tid; t2 < (np2 >> 1); t2 += 1024) {
        int pos = 2 * t2 - (t2 & (stride - 1));
        int qq = pos + stride;
        bool up = ((pos & size) == 0);
        float v1 = s_sval[pos], v2 = s_sval[qq];
        int i1 = s_sidx[pos], i2 = s_sidx[qq];
        bool gt = (v1 > v2) || (v1 == v2 && i1 > i2);
        if (gt == up) {
          s_sval[pos] = v2; s_sval[qq] = v1;
          s_sidx[pos] = i2; s_sidx[qq] = i1;
        }
      }
      __syncthreads();
    }
  }
  const int kk = k > G ? G : k;
  const float kth = s_sval[G - kk];
  const float m = s_m;
  for (int i = tid; i < G; i += 1024) {
    if (s_sval[i] >= kth && (i == 0 || s_sval[i - 1] < kth)) s_p0 = i;
  }
  __syncthreads();
  const int p0 = s_p0;
  float part = 0.0f;
  for (int i = p0 + tid; i < G; i += 1024) {
    float e = expf(s_sval[i] - m);
    s_e[i] = e;
    part += e;
  }
#pragma unroll
  for (int d = 32; d > 0; d >>= 1) part += __shfl_xor(part, d);
  if (lane == 0) s_wredf[wid] = part;
  __syncthreads();
  if (tid == 0) {
    float s = 0.0f;
    for (int i = 0; i < 16; ++i) s += s_wredf[i];
    s_denom = s;
  }
  __syncthreads();
  const float denom = s_denom;
  if (tid == 0) {
    const float cut = 1.0f - topp;
    float cs = 0.0f;
    for (int i = p0; i < G; ++i) {
      cs += s_e[i] / denom;
      s_keep[i] = (cs <= cut) ? 0 : 1;
    }
    s_keep[G - 1] = 1;
  }
  __syncthreads();
  part = 0.0f;
  for (int i = p0 + tid; i < G; i += 1024)
    if (s_keep[i]) part += s_e[i];
#pragma unroll
  for (int d = 32; d > 0; d >>= 1) part += __shfl_xor(part, d);
  if (lane == 0) s_wredf[wid] = part;
  __syncthreads();
  if (tid == 0) {
    float s = 0.0f;
    for (int i = 0; i < 16; ++i) s += s_wredf[i];
    s_denom2 = s;
  }
  __syncthreads();
  const float denom2 = s_denom2;
  for (int i = p0 + tid; i < G; i += 1024)
    s_e[i] = s_keep[i] ? (s_e[i] / denom2) : 0.0f;
  __syncthreads();
  float bs = -INFINITY;
  int bi = 0x7FFFFFFF;
  for (int i = p0 + tid; i < G; i += 1024) {
    if (!s_keep[i]) continue;
    int j = s_sidx[i];
    unsigned int t = (unsigned int)(row * V) + (unsigned int)j;
    unsigned int bb = tf_bits(t);
    float u = __uint_as_float((bb >> 9) | 0x3f800000u) - 1.0f;
    if (u < TINYF) u = TINYF;
    float g = -logf(-logf(u));
    float sc = s_sval[i] + g;
    if (sc > bs || (sc == bs && j < bi)) { bs = sc; bi = j; }
  }
  const unsigned int kkey = fkey(kth);
  const int k16 = (int)(kkey >> 16);
  for (int q = tid; q < V4; q += 1024) {
    vfloat4 o = (vfloat4){0.0f, 0.0f, 0.0f, 0.0f};
    if ((int)s_cmax16[q >> 2] >= k16) {
      float4 x4 = lg4[q];
      float raw[4] = {x4.x, x4.y, x4.z, x4.w};
      float os[4];
      const int j0 = q * 4;
      const int sh = j0 & 31;
      unsigned long long ww = (unsigned long long)s_seen[j0 >> 5] |
                              ((unsigned long long)s_seen[(j0 + 3) >> 5] << 32);
#pragma unroll
      for (int e = 0; e < 4; ++e) {
        float x = xform(raw[e], (ww >> (sh + e)) & 1ull, rp, irp, itemp);
        float pr = 0.0f;
        if (x >= kth) {
          int j = j0 + e;
          int lo = p0, hi = G;
          while (lo < hi) {
            int mid = (lo + hi) >> 1;
            float v = s_sval[mid];
            int id = s_sidx[mid];
            if (v < x || (v == x && id < j)) lo = mid + 1; else hi = mid;
          }
          pr = s_e[lo];
        }
        os[e] = pr;
      }
      o.x = os[0]; o.y = os[1]; o.z = os[2]; o.w = os[3];
    }
    pr4[q] = o;
  }
#pragma unroll
  for (int d = 32; d > 0; d >>= 1) {
    float ov = __shfl_down(bs, d);
    int oi = __shfl_down(bi, d);
    if (ov > bs || (ov == bs && oi < bi)) { bs = ov; bi = oi; }
  }
  if (lane == 0) { s_wredf[wid] = bs; s_wredi[wid] = bi; }
  __syncthreads();
  if (tid == 0) {
    float bb = s_wredf[0];
    int bj = s_wredi[0];
    for (int i = 1; i < 16; ++i) {
      if (s_wredf[i] > bb || (s_wredf[i] == bb && s_wredi[i] < bj)) {
        bb = s_wredf[i];
        bj = s_wredi[i];
      }
    }
    out_ids[row] = (float)bj;
  }
}

extern "C" void kernel_launch(void* const* d_in, const int* in_sizes, int n_in,
                              void* d_out, int out_size, void* d_ws, size_t ws_size,
                              hipStream_t stream) {
  (void)in_sizes; (void)out_size;
  if (n_in < 6) return;
  const float* logits = (const float*)d_in[0];
  const int* toks = (const int*)d_in[1];
  const float* temps = (const float*)d_in[2];
  const float* topps = (const float*)d_in[3];
  const int* topks = (const int*)d_in[4];
  const float* rps = (const float*)d_in[5];
  float* out = (float*)d_out;            // [0,256): ids as float; [256,...): probs
  float* probs = out + NROWS;

  if (ws_size >= WS_NEED && d_ws != nullptr) {
    char* w = (char*)d_ws;
    unsigned short* ws_cmax = (unsigned short*)(w + WS_CMAX);
    float* ws_bmax = (float*)(w + WS_BMAX);
    int* ws_b0 = (int*)(w + WS_B0);
    int* ws_cnt8 = (int*)(w + WS_CNT8);
    int* ws_ovf = (int*)(w + WS_OVF);
    unsigned long long* ws_keys = (unsigned long long*)(w + WS_KEYS);
    kA_chunkmax<<<dim3(NROWS * NSLICE), dim3(256), 0, stream>>>(
        logits, toks, temps, rps, ws_cmax, ws_bmax);
    kS_b0<<<dim3(NROWS), dim3(1024), 0, stream>>>(ws_cmax, topks, ws_b0, ws_ovf);
    kB1_gather<<<dim3(NROWS * NSLICE), dim3(256), 0, stream>>>(
        logits, toks, temps, rps, ws_cmax, ws_b0, ws_cnt8, ws_ovf, ws_keys, probs);
    kB2_finish<<<dim3(NROWS), dim3(1024), 0, stream>>>(
        topps, topks, ws_bmax, ws_cnt8, ws_ovf, ws_keys, out, probs);
  } else {
    sampler_mono<<<dim3(NROWS), dim3(1024), 0, stream>>>(
        logits, toks, temps, topps, topks, rps, out, probs);
  }
}